// Round 5
// baseline (482.147 us; speedup 1.0000x reference)
//
#include <hip/hip_runtime.h>
#include <hip/hip_cooperative_groups.h>
#include <hip/hip_bf16.h>
#include <math.h>

namespace cg = cooperative_groups;

// Problem constants
#define BB 64
#define SS 2048
#define HH 1024
#define EE 1024
#define DD 64          // window half-size
#define G4H 4096       // 4*H
#define KS1 8          // k-splits for gates GEMM (K=3072, kchunk=384)
#define KS2 16         // k-splits for H=1024 GEMMs (kchunk=64)

typedef __attribute__((ext_vector_type(8))) short short8;
typedef __attribute__((ext_vector_type(4))) float floatx4;

#define MFMA_BF16(a, b, c) __builtin_amdgcn_mfma_f32_16x16x32_bf16((a), (b), (c), 0, 0, 0)

__device__ __forceinline__ float sigmoidf_(float x) { return 1.0f / (1.0f + expf(-x)); }

__device__ __forceinline__ ushort f2bf(float f) {
    return __builtin_bit_cast(ushort, __float2bfloat16(f));
}
__device__ __forceinline__ float bf2f(ushort h) {
    return __uint_as_float(((uint)h) << 16);
}

// split float4 into hi/lo bf16 pairs and store to LDS tiles (row stride 72 ushorts = 144 B)
__device__ __forceinline__ void stage_split(ushort* hbase, ushort* lbase, int row, int col, float4 v) {
    const ushort hx = f2bf(v.x), hy = f2bf(v.y), hz = f2bf(v.z), hw = f2bf(v.w);
    const float  lx = v.x - bf2f(hx), ly = v.y - bf2f(hy);
    const float  lz = v.z - bf2f(hz), lw = v.w - bf2f(hw);
    uint2 hp, lp;
    hp.x = (uint)hx | ((uint)hy << 16);
    hp.y = (uint)hz | ((uint)hw << 16);
    lp.x = (uint)f2bf(lx) | ((uint)f2bf(ly) << 16);
    lp.y = (uint)f2bf(lz) | ((uint)f2bf(lw) << 16);
    *(uint2*)(hbase + row * 72 + col) = hp;
    *(uint2*)(lbase + row * 72 + col) = lp;
}

// bf16x3 split-MFMA partial GEMM phase (64j x 64b tile, k in [k0, k0+kchunk)).
// partOut[j*64+b] for j within tile. smemRaw needs 36864 B.
__device__ __forceinline__ void gemm_phase(
    const float* __restrict__ X1, int x1ld,
    const float* __restrict__ X2, int x2ld,
    const float* __restrict__ W1, int w1ld,
    const float* __restrict__ W2, int w2ld,
    int k1len, int k0, int kchunk, int jt, int Jtot,
    float* __restrict__ partOut, char* smemRaw)
{
    const int t = threadIdx.x;
    const int c = t & 15;             // staging k-col group (4 floats)
    const int r = t >> 4;             // staging row group
    const int lane = t & 63;
    const int wj   = t >> 6;          // wave id = j-subtile (0..3)
    const int rr   = lane & 15;       // A: row (j), B: col (b)
    const int kg   = lane >> 4;       // k-group: lane holds k = kg*8 .. kg*8+7

    ushort (*Wh)[72] = (ushort(*)[72])(smemRaw);
    ushort (*Wl)[72] = (ushort(*)[72])(smemRaw + 9216);
    ushort (*Xh)[72] = (ushort(*)[72])(smemRaw + 18432);
    ushort (*Xl)[72] = (ushort(*)[72])(smemRaw + 27648);

    floatx4 acc[4];
#pragma unroll
    for (int bs = 0; bs < 4; ++bs) acc[bs] = (floatx4){0.f, 0.f, 0.f, 0.f};

    for (int kk = k0; kk < k0 + kchunk; kk += 64) {
        const int kg4 = kk + 4 * c;
#pragma unroll
        for (int i = 0; i < 4; ++i) {
            const int row = r + 16 * i;   // 0..63
            const float* xs = (kg4 < k1len) ? (X1 + (size_t)row * x1ld + kg4)
                                            : (X2 + (size_t)row * x2ld + (kg4 - k1len));
            float4 xv = *(const float4*)xs;
            const int j = jt * 64 + row;
            const float* wsrc = (kg4 < k1len) ? (W1 + (size_t)j * w1ld + kg4)
                                              : (W2 + (size_t)j * w2ld + (kg4 - k1len));
            float4 wv = *(const float4*)wsrc;
            stage_split(&Xh[0][0], &Xl[0][0], row, 4 * c, xv);
            stage_split(&Wh[0][0], &Wl[0][0], row, 4 * c, wv);
        }
        __syncthreads();

        const int aoff = (wj * 16 + rr) * 72 + kg * 8;
        short8 ah[2], al[2];
        ah[0] = *(const short8*)((const void*)(&Wh[0][0] + aoff));
        ah[1] = *(const short8*)((const void*)(&Wh[0][0] + aoff + 32));
        al[0] = *(const short8*)((const void*)(&Wl[0][0] + aoff));
        al[1] = *(const short8*)((const void*)(&Wl[0][0] + aoff + 32));

#pragma unroll
        for (int bs = 0; bs < 4; ++bs) {
            const int boff = (bs * 16 + rr) * 72 + kg * 8;
#pragma unroll
            for (int kh = 0; kh < 2; ++kh) {
                short8 bh = *(const short8*)((const void*)(&Xh[0][0] + boff + kh * 32));
                short8 bl = *(const short8*)((const void*)(&Xl[0][0] + boff + kh * 32));
                acc[bs] = MFMA_BF16(ah[kh], bh, acc[bs]);   // hi*hi
                acc[bs] = MFMA_BF16(al[kh], bh, acc[bs]);   // lo*hi
                acc[bs] = MFMA_BF16(ah[kh], bl, acc[bs]);   // hi*lo
            }
        }
        __syncthreads();
    }

    // C/D layout: col = lane&15 (b), row = (lane>>4)*4 + reg (j within subtile)
#pragma unroll
    for (int bs = 0; bs < 4; ++bs) {
#pragma unroll
        for (int reg = 0; reg < 4; ++reg) {
            const int j = wj * 16 + kg * 4 + reg;
            const int b = bs * 16 + rr;
            partOut[(size_t)j * BB + b] = acc[bs][reg];
        }
    }
}

struct KArgs {
    const float* encode_h;
    const float* x_t;
    const float* h0;
    const float* c0;
    const float* W_ih;
    const float* W_hh;
    const float* b_ih;
    const float* b_hh;
    const float* W_ht2tan;
    const float* W_tan2pt;
    const float* W_ct2ht;
    const int*   elen;
    float*       out;
    float*       ws;
};

// One cooperative kernel for the whole chain. grid = 512 x 256 threads.
// 2 blocks/CU co-resident (LDS 36.9 KB, VGPR capped by launch_bounds).
__global__ __launch_bounds__(256, 2) void nmt_mega(KArgs A)
{
    cg::grid_group grid = cg::this_grid();
    __shared__ __align__(16) char smem[36864];

    const int blk = blockIdx.x;
    const int t   = threadIdx.x;
    const int lane = t & 63;

    float* gates_part = A.ws;                                 // KS1*4096*64
    float* yt    = gates_part + (size_t)KS1 * G4H * BB;       // 65536
    float* part2 = yt + (size_t)BB * HH;                      // KS2*1024*64
    float* pbuf  = part2 + (size_t)KS2 * HH * BB;             // 64
    int*   lrbuf = (int*)(pbuf + BB);                         // 128 ints
    float* scbuf = pbuf + BB + 2 * BB;                        // 64*128
    float* ctbuf = scbuf + (size_t)BB * 2 * DD;               // 65536
    float* part3 = ctbuf + (size_t)BB * HH;                   // KS2*1024*64

    // ---- P1: gates GEMM, 512 tasks = 64 jt x 8 ks (kchunk 384) ----
    {
        const int jt = blk >> 3;
        const int ks = blk & 7;
        gemm_phase(A.x_t, EE + HH, A.h0, HH, A.W_ih, EE + HH, A.W_hh, HH,
                   2048, ks * 384, 384, jt, G4H,
                   gates_part + ((size_t)ks * G4H + jt * 64) * BB, smem);
    }
    grid.sync();

    // ---- P2: LSTM cell -> yt, 256 blocks x (4 h, 64 b) ----
    if (blk < 256) {
        const int b = t & 63;
        const int h = blk * 4 + (t >> 6);
        float g4[4];
#pragma unroll
        for (int q = 0; q < 4; ++q) {
            const int j = h + q * HH;
            float s = A.b_ih[j] + A.b_hh[j];
#pragma unroll
            for (int ks = 0; ks < KS1; ++ks)
                s += gates_part[((size_t)ks * G4H + j) * BB + b];
            g4[q] = s;
        }
        const float ig = sigmoidf_(g4[0]);
        const float fg = sigmoidf_(g4[1]);
        const float gg = tanhf(g4[2]);
        const float og = sigmoidf_(g4[3]);
        const float c  = fg * A.c0[(size_t)b * HH + h] + ig * gg;
        yt[(size_t)b * HH + h] = og * tanhf(c);
    }
    grid.sync();

    // ---- P3: t1 = yt @ W_ht2tan^T, 256 tasks = 16 jt x 16 ks (kchunk 64) ----
    if (blk < 256) {
        const int jt = blk >> 4;
        const int ks = blk & 15;
        gemm_phase(yt, HH, yt, HH, A.W_ht2tan, HH, A.W_ht2tan, HH,
                   HH, ks * 64, 64, jt, HH,
                   part2 + ((size_t)ks * HH + jt * 64) * BB, smem);
    }
    grid.sync();

    // ---- P4: p + window bounds, 64 blocks ----
    if (blk < 64) {
        const int b = blk;
        float* red = (float*)smem;
        float acc = 0.0f;
        for (int i = t; i < HH; i += 256) {
            float s = 0.0f;
#pragma unroll
            for (int ks = 0; ks < KS2; ++ks)
                s += part2[((size_t)ks * HH + i) * BB + b];
            acc += tanhf(s) * A.W_tan2pt[i];
        }
        red[t] = acc;
        __syncthreads();
        if (t < 128) red[t] += red[t + 128];
        __syncthreads();
        if (t < 64) {
            float x = red[t] + red[t + 64];
#pragma unroll
            for (int off = 32; off; off >>= 1) x += __shfl_xor(x, off);
            if (t == 0) {
                const float pt  = sigmoidf_(x);
                const float len = (float)A.elen[b];
                const float p   = len * pt;
                const int   pf  = (int)floorf(p);
                const int   left  = max(0, pf - DD);
                const int   right = min(A.elen[b], pf + DD);
                pbuf[b] = p;
                lrbuf[b * 2 + 0] = left;
                lrbuf[b * 2 + 1] = right;
            }
        }
    }
    grid.sync();

    // ---- P5: windowed raw scores, 512 tasks = 64 b x 8 q (4 si per wave) ----
    {
        const int b = blk >> 3;
        const int q = blk & 7;
        const int wv = t >> 6;
        float* yts = (float*)smem;   // 4 KB
        *(float4*)&yts[t * 4] = *(const float4*)&yt[(size_t)b * HH + t * 4];
        const int left = lrbuf[b * 2], right = lrbuf[b * 2 + 1];
        const int wsize = right - left;
        __syncthreads();

#pragma unroll
        for (int rr = 0; rr < 4; ++rr) {
            const int si = q * 16 + wv * 4 + rr;
            float s = -1e30f;
            if (si < wsize) {
                const float* eh = A.encode_h + ((size_t)b * SS + (left + si)) * HH;
                s = 0.0f;
#pragma unroll
                for (int cc = 0; cc < 4; ++cc) {
                    const int hb = cc * 256 + lane * 4;
                    float4 e = *(const float4*)(eh + hb);
                    s += e.x * yts[hb] + e.y * yts[hb + 1] + e.z * yts[hb + 2] + e.w * yts[hb + 3];
                }
#pragma unroll
                for (int off = 32; off; off >>= 1) s += __shfl_xor(s, off);
            }
            if (lane == 0) scbuf[b * 2 * DD + si] = s;
        }
    }
    grid.sync();

    // ---- P6: softmax + gauss + ct, 256 tasks = 64 b x 4 hchunk(256) ----
    if (blk < 256) {
        const int b = blk >> 2;
        const int h = (blk & 3) * 256 + t;
        float* scs = (float*)smem;          // 512 B
        float* ats = (float*)smem + 128;    // 512 B

        const int left = lrbuf[b * 2];
        if (t < 2 * DD) scs[t] = scbuf[b * 2 * DD + t];
        __syncthreads();

        float m = fmaxf(scs[lane], scs[lane + 64]);
#pragma unroll
        for (int off = 32; off; off >>= 1) m = fmaxf(m, __shfl_xor(m, off));
        float ssum = expf(scs[lane] - m) + expf(scs[lane + 64] - m);
#pragma unroll
        for (int off = 32; off; off >>= 1) ssum += __shfl_xor(ssum, off);
        const float inv = 1.0f / ssum;

        if (t < 2 * DD) {
            const float dj = (float)(left + t) - pbuf[b];
            ats[t] = expf(scs[t] - m) * inv * expf(-(dj * dj) * (1.0f / 2048.0f));
        }
        __syncthreads();

        const float* ehb = A.encode_h + ((size_t)b * SS + left) * HH + h;
        float a0 = 0, a1 = 0, a2 = 0, a3 = 0, a4 = 0, a5 = 0, a6 = 0, a7 = 0;
#pragma unroll 2
        for (int si = 0; si < 2 * DD; si += 8) {
            a0 = fmaf(ats[si + 0], ehb[(size_t)(si + 0) * HH], a0);
            a1 = fmaf(ats[si + 1], ehb[(size_t)(si + 1) * HH], a1);
            a2 = fmaf(ats[si + 2], ehb[(size_t)(si + 2) * HH], a2);
            a3 = fmaf(ats[si + 3], ehb[(size_t)(si + 3) * HH], a3);
            a4 = fmaf(ats[si + 4], ehb[(size_t)(si + 4) * HH], a4);
            a5 = fmaf(ats[si + 5], ehb[(size_t)(si + 5) * HH], a5);
            a6 = fmaf(ats[si + 6], ehb[(size_t)(si + 6) * HH], a6);
            a7 = fmaf(ats[si + 7], ehb[(size_t)(si + 7) * HH], a7);
        }
        ctbuf[(size_t)b * HH + h] = ((a0 + a1) + (a2 + a3)) + ((a4 + a5) + (a6 + a7));
    }
    grid.sync();

    // ---- P7: ht partials = ct @ W_ct2ht^T, 256 tasks ----
    if (blk < 256) {
        const int jt = blk >> 4;
        const int ks = blk & 15;
        gemm_phase(ctbuf, HH, ctbuf, HH, A.W_ct2ht, HH, A.W_ct2ht, HH,
                   HH, ks * 64, 64, jt, HH,
                   part3 + ((size_t)ks * HH + jt * 64) * BB, smem);
    }
    grid.sync();

    // ---- P8: reduce -> out, 256 blocks x (4 j, 64 b) ----
    if (blk < 256) {
        const int b = t & 63;
        const int j = blk * 4 + (t >> 6);
        float s = 0.0f;
#pragma unroll
        for (int ks = 0; ks < KS2; ++ks)
            s += part3[((size_t)ks * HH + j) * BB + b];
        A.out[(size_t)b * HH + j] = s;
    }
}

extern "C" void kernel_launch(void* const* d_in, const int* in_sizes, int n_in,
                              void* d_out, int out_size, void* d_ws, size_t ws_size,
                              hipStream_t stream)
{
    KArgs A;
    A.encode_h = (const float*)d_in[0];
    A.x_t      = (const float*)d_in[1];
    A.h0       = (const float*)d_in[2];
    A.c0       = (const float*)d_in[3];
    A.W_ih     = (const float*)d_in[4];
    A.W_hh     = (const float*)d_in[5];
    A.b_ih     = (const float*)d_in[6];
    A.b_hh     = (const float*)d_in[7];
    A.W_ht2tan = (const float*)d_in[8];
    A.W_tan2pt = (const float*)d_in[9];
    A.W_ct2ht  = (const float*)d_in[10];
    A.elen     = (const int*)d_in[11];
    A.out      = (float*)d_out;
    A.ws       = (float*)d_ws;

    void* params[] = { (void*)&A };
    hipLaunchCooperativeKernel((const void*)nmt_mega, dim3(512), dim3(256),
                               params, 0, stream);
}

// Round 7
// 198.083 us; speedup vs baseline: 2.4341x; 2.4341x over previous
//
#include <hip/hip_runtime.h>
#include <hip/hip_bf16.h>
#include <math.h>

// Problem constants
#define BB 64
#define SS 2048
#define HH 1024
#define EE 1024
#define DD 64          // window half-size
#define G4H 4096       // 4*H
#define KS3 4          // k-splits for the t1 (H=1024) GEMM

typedef __attribute__((ext_vector_type(8))) short short8;
typedef __attribute__((ext_vector_type(4))) float floatx4;

#define MFMA_BF16(a, b, c) __builtin_amdgcn_mfma_f32_16x16x32_bf16((a), (b), (c), 0, 0, 0)

__device__ __forceinline__ float sigmoidf_(float x) { return 1.0f / (1.0f + expf(-x)); }

__device__ __forceinline__ ushort f2bf(float f) {
    return __builtin_bit_cast(ushort, __float2bfloat16(f));
}
__device__ __forceinline__ float bf2f(ushort h) {
    return __uint_as_float(((uint)h) << 16);
}

// split float4 into hi/lo bf16 pairs, store to LDS tiles (row stride 72 ushorts = 144 B)
__device__ __forceinline__ void stage_split(ushort* hbase, ushort* lbase, int row, int col, float4 v) {
    const ushort hx = f2bf(v.x), hy = f2bf(v.y), hz = f2bf(v.z), hw = f2bf(v.w);
    const float  lx = v.x - bf2f(hx), ly = v.y - bf2f(hy);
    const float  lz = v.z - bf2f(hz), lw = v.w - bf2f(hw);
    uint2 hp, lp;
    hp.x = (uint)hx | ((uint)hy << 16);
    hp.y = (uint)hz | ((uint)hw << 16);
    lp.x = (uint)f2bf(lx) | ((uint)f2bf(ly) << 16);
    lp.y = (uint)f2bf(lz) | ((uint)f2bf(lw) << 16);
    *(uint2*)(hbase + row * 72 + col) = hp;
    *(uint2*)(lbase + row * 72 + col) = lp;
}

// K1: fused gates-GEMM + LSTM cell. grid = 256 blocks (h-tile of 4), block = 256.
// A-tile = 16 j rows {g*1024 + hbase + r : g,r in 0..3}, K = 3072 concat:
//   k < 2048 -> x_t (ld 2048) / W_ih (ld 2048);  k >= 2048 -> h0 (ld 1024) / W_hh (ld 1024).
// B = 64 batch rows. Wave w owns b-subtile w. bf16x3 split for fp32-class accuracy.
__global__ __launch_bounds__(256) void gates_lstm(
    const float* __restrict__ x_t, const float* __restrict__ h0m,
    const float* __restrict__ W_ih, const float* __restrict__ W_hh,
    const float* __restrict__ b_ih, const float* __restrict__ b_hh,
    const float* __restrict__ c0, float* __restrict__ yt)
{
    const int hbase = blockIdx.x * 4;
    const int t = threadIdx.x;
    const int c = t & 15;            // staging k-col group (4 floats)
    const int r = t >> 4;            // staging row group (0..15)
    const int lane = t & 63;
    const int w = t >> 6;            // wave = b-subtile
    const int rr = lane & 15;
    const int kg = lane >> 4;

    __shared__ __align__(16) ushort Ah[16][72], Al[16][72];   // weight rows
    __shared__ __align__(16) ushort Xh[64][72], Xl[64][72];   // batch rows
    __shared__ float gsm[4][4][64];                           // [gate][h][b]

    floatx4 acc = (floatx4){0.f, 0.f, 0.f, 0.f};

    for (int kk = 0; kk < 3072; kk += 64) {
        const int kg4 = kk + 4 * c;
        // stage X: 64 rows (x_t ld 2048 | h0 ld 1024)
#pragma unroll
        for (int i = 0; i < 4; ++i) {
            const int row = r + 16 * i;
            const float* xs = (kg4 < 2048) ? (x_t + (size_t)row * 2048 + kg4)
                                           : (h0m + (size_t)row * 1024 + (kg4 - 2048));
            stage_split(&Xh[0][0], &Xl[0][0], row, 4 * c, *(const float4*)xs);
        }
        // stage W: 16 rows; row r -> j = (r>>2)*1024 + hbase + (r&3)  (W_ih ld 2048 | W_hh ld 1024)
        {
            const int j = (r >> 2) * 1024 + hbase + (r & 3);
            const float* wsrc = (kg4 < 2048) ? (W_ih + (size_t)j * 2048 + kg4)
                                             : (W_hh + (size_t)j * 1024 + (kg4 - 2048));
            stage_split(&Ah[0][0], &Al[0][0], r, 4 * c, *(const float4*)wsrc);
        }
        __syncthreads();

        const int aoff = rr * 72 + kg * 8;
        const int boff = (w * 16 + rr) * 72 + kg * 8;
#pragma unroll
        for (int kh = 0; kh < 2; ++kh) {
            short8 ah = *(const short8*)((const void*)(&Ah[0][0] + aoff + kh * 32));
            short8 al = *(const short8*)((const void*)(&Al[0][0] + aoff + kh * 32));
            short8 bh = *(const short8*)((const void*)(&Xh[0][0] + boff + kh * 32));
            short8 bl = *(const short8*)((const void*)(&Xl[0][0] + boff + kh * 32));
            acc = MFMA_BF16(ah, bh, acc);
            acc = MFMA_BF16(al, bh, acc);
            acc = MFMA_BF16(ah, bl, acc);
        }
        __syncthreads();
    }

    // C/D: row (j-within-16) = kg*4+reg -> gate kg, h-offset reg; col (b-within-16) = rr
#pragma unroll
    for (int reg = 0; reg < 4; ++reg)
        gsm[kg][reg][w * 16 + rr] = acc[reg];
    __syncthreads();

    {
        const int b = t & 63;
        const int rh = t >> 6;                 // 0..3
        const int h = hbase + rh;
        const float bi = b_ih[0 * HH + h] + b_hh[0 * HH + h];
        const float bf = b_ih[1 * HH + h] + b_hh[1 * HH + h];
        const float bg = b_ih[2 * HH + h] + b_hh[2 * HH + h];
        const float bo = b_ih[3 * HH + h] + b_hh[3 * HH + h];
        const float ig = sigmoidf_(gsm[0][rh][b] + bi);
        const float fg = sigmoidf_(gsm[1][rh][b] + bf);
        const float gg = tanhf(gsm[2][rh][b] + bg);
        const float og = sigmoidf_(gsm[3][rh][b] + bo);
        const float cc = fg * c0[(size_t)b * HH + h] + ig * gg;
        yt[(size_t)b * HH + h] = og * tanhf(cc);
    }
}

// bf16x3 split-MFMA partial GEMM: part[ks][j][b] = sum_{k in chunk} X(b,k)*W(j,k)
// grid=(Jtot/64, KS), block=256.
__global__ __launch_bounds__(256) void gemm_mfma(
    const float* __restrict__ X1, int x1ld,
    const float* __restrict__ W1, int w1ld,
    int Ktot, int Jtot,
    float* __restrict__ part)
{
    const int jt = blockIdx.x;
    const int ks = blockIdx.y;
    const int KS = gridDim.y;
    const int kchunk = Ktot / KS;
    const int k0 = ks * kchunk;
    const int t  = threadIdx.x;

    const int c = t & 15;
    const int r = t >> 4;
    const int lane = t & 63;
    const int wj   = t >> 6;
    const int rr   = lane & 15;
    const int kg   = lane >> 4;

    __shared__ __align__(16) ushort Wh[64][72];
    __shared__ __align__(16) ushort Wl[64][72];
    __shared__ __align__(16) ushort Xh[64][72];
    __shared__ __align__(16) ushort Xl[64][72];

    floatx4 acc[4];
#pragma unroll
    for (int bs = 0; bs < 4; ++bs) acc[bs] = (floatx4){0.f, 0.f, 0.f, 0.f};

    for (int kk = k0; kk < k0 + kchunk; kk += 64) {
        const int kg4 = kk + 4 * c;
#pragma unroll
        for (int i = 0; i < 4; ++i) {
            const int row = r + 16 * i;
            stage_split(&Xh[0][0], &Xl[0][0], row, 4 * c,
                        *(const float4*)(X1 + (size_t)row * x1ld + kg4));
            const int j = jt * 64 + row;
            stage_split(&Wh[0][0], &Wl[0][0], row, 4 * c,
                        *(const float4*)(W1 + (size_t)j * w1ld + kg4));
        }
        __syncthreads();

        const int aoff = (wj * 16 + rr) * 72 + kg * 8;
        short8 ah[2], al[2];
        ah[0] = *(const short8*)((const void*)(&Wh[0][0] + aoff));
        ah[1] = *(const short8*)((const void*)(&Wh[0][0] + aoff + 32));
        al[0] = *(const short8*)((const void*)(&Wl[0][0] + aoff));
        al[1] = *(const short8*)((const void*)(&Wl[0][0] + aoff + 32));

#pragma unroll
        for (int bs = 0; bs < 4; ++bs) {
            const int boff = (bs * 16 + rr) * 72 + kg * 8;
#pragma unroll
            for (int kh = 0; kh < 2; ++kh) {
                short8 bh = *(const short8*)((const void*)(&Xh[0][0] + boff + kh * 32));
                short8 bl = *(const short8*)((const void*)(&Xl[0][0] + boff + kh * 32));
                acc[bs] = MFMA_BF16(ah[kh], bh, acc[bs]);
                acc[bs] = MFMA_BF16(al[kh], bh, acc[bs]);
                acc[bs] = MFMA_BF16(ah[kh], bl, acc[bs]);
            }
        }
        __syncthreads();
    }

#pragma unroll
    for (int bs = 0; bs < 4; ++bs) {
#pragma unroll
        for (int reg = 0; reg < 4; ++reg) {
            const int j = jt * 64 + wj * 16 + kg * 4 + reg;
            const int b = bs * 16 + rr;
            part[((size_t)ks * Jtot + j) * BB + b] = acc[bs][reg];
        }
    }
}

// p_t = len * sigmoid( sum_i tanh(t1[b][i]) * v[i] ); window bounds. grid = B.
__global__ __launch_bounds__(256) void pos_kernel(
    const float* __restrict__ part2, const float* __restrict__ v,
    const int* __restrict__ elen,
    float* __restrict__ p_out, int* __restrict__ lr_out)
{
    const int b = blockIdx.x;
    const int t = threadIdx.x;
    float acc = 0.0f;
    for (int i = t; i < HH; i += 256) {
        float s = 0.0f;
#pragma unroll
        for (int ks = 0; ks < KS3; ++ks)
            s += part2[((size_t)ks * HH + i) * BB + b];
        acc += tanhf(s) * v[i];
    }
    __shared__ float red[256];
    red[t] = acc;
    __syncthreads();
    if (t < 128) red[t] += red[t + 128];
    __syncthreads();
    if (t < 64) {
        float x = red[t] + red[t + 64];
#pragma unroll
        for (int off = 32; off; off >>= 1) x += __shfl_xor(x, off);
        if (t == 0) {
            const float pt  = sigmoidf_(x);
            const float len = (float)elen[b];
            const float p   = len * pt;
            const int   pf  = (int)floorf(p);
            const int   left  = max(0, pf - DD);
            const int   right = min(elen[b], pf + DD);
            p_out[b] = p;
            lr_out[b * 2 + 0] = left;
            lr_out[b * 2 + 1] = right;
        }
    }
}

// Windowed raw scores. grid = (B, 8), block = 256 (4 waves, 4 si each).
__global__ __launch_bounds__(256) void attn_scores(
    const float* __restrict__ encode_h, const float* __restrict__ yt,
    const int* __restrict__ lr, float* __restrict__ sc_out)
{
    const int b = blockIdx.x;
    const int q = blockIdx.y;
    const int t = threadIdx.x;
    const int lane = t & 63;
    const int wv = t >> 6;

    __shared__ float yts[HH];
    *(float4*)&yts[t * 4] = *(const float4*)&yt[(size_t)b * HH + t * 4];
    const int left = lr[b * 2], right = lr[b * 2 + 1];
    const int wsize = right - left;
    __syncthreads();

#pragma unroll
    for (int rr = 0; rr < 4; ++rr) {
        const int si = q * 16 + wv * 4 + rr;
        float s = -1e30f;
        if (si < wsize) {
            const float* eh = encode_h + ((size_t)b * SS + (left + si)) * HH;
            s = 0.0f;
#pragma unroll
            for (int cc = 0; cc < 4; ++cc) {
                const int hb = cc * 256 + lane * 4;
                float4 e = *(const float4*)(eh + hb);
                s += e.x * yts[hb] + e.y * yts[hb + 1] + e.z * yts[hb + 2] + e.w * yts[hb + 3];
            }
#pragma unroll
            for (int off = 32; off; off >>= 1) s += __shfl_xor(s, off);
        }
        if (lane == 0) sc_out[b * 2 * DD + si] = s;
    }
}

// Fused softmax+gauss+ct: grid = (B, 4), block = 512; half-split over si.
__global__ __launch_bounds__(512) void attn_ct(
    const float* __restrict__ encode_h, const float* __restrict__ sc,
    const float* __restrict__ p_buf, const int* __restrict__ lr,
    float* __restrict__ ct)
{
    const int b = blockIdx.x;
    const int t = threadIdx.x;
    const int lane = t & 63;
    const int hh = t & 255;
    const int half = t >> 8;
    const int h = blockIdx.y * 256 + hh;

    __shared__ float scs[2 * DD];
    __shared__ float ats[2 * DD];
    __shared__ float red[256];

    const int left = lr[b * 2];
    if (t < 2 * DD) scs[t] = sc[b * 2 * DD + t];
    __syncthreads();

    float m = fmaxf(scs[lane], scs[lane + 64]);
#pragma unroll
    for (int off = 32; off; off >>= 1) m = fmaxf(m, __shfl_xor(m, off));
    float ssum = expf(scs[lane] - m) + expf(scs[lane + 64] - m);
#pragma unroll
    for (int off = 32; off; off >>= 1) ssum += __shfl_xor(ssum, off);
    const float inv = 1.0f / ssum;

    if (t < 2 * DD) {
        const float dj = (float)(left + t) - p_buf[b];
        ats[t] = expf(scs[t] - m) * inv * expf(-(dj * dj) * (1.0f / 2048.0f));
    }
    __syncthreads();

    const float* ehb = encode_h + ((size_t)b * SS + left + half * 64) * HH + h;
    const float* atp = &ats[half * 64];
    float a0 = 0, a1 = 0, a2 = 0, a3 = 0, a4 = 0, a5 = 0, a6 = 0, a7 = 0;
#pragma unroll 2
    for (int si = 0; si < 64; si += 8) {
        a0 = fmaf(atp[si + 0], ehb[(size_t)(si + 0) * HH], a0);
        a1 = fmaf(atp[si + 1], ehb[(size_t)(si + 1) * HH], a1);
        a2 = fmaf(atp[si + 2], ehb[(size_t)(si + 2) * HH], a2);
        a3 = fmaf(atp[si + 3], ehb[(size_t)(si + 3) * HH], a3);
        a4 = fmaf(atp[si + 4], ehb[(size_t)(si + 4) * HH], a4);
        a5 = fmaf(atp[si + 5], ehb[(size_t)(si + 5) * HH], a5);
        a6 = fmaf(atp[si + 6], ehb[(size_t)(si + 6) * HH], a6);
        a7 = fmaf(atp[si + 7], ehb[(size_t)(si + 7) * HH], a7);
    }
    const float a = ((a0 + a1) + (a2 + a3)) + ((a4 + a5) + (a6 + a7));

    if (half == 1) red[hh] = a;
    __syncthreads();
    if (half == 0) ct[(size_t)b * HH + h] = a + red[hh];
}

// Final GEMM with swapped roles: out[b][j] = sum_k ct[b][k]*W[j][k], direct [b][j] write.
// A-operand = ct rows (b), B-operand = W rows (j). grid = 16 (j-tiles of 64), full K.
__global__ __launch_bounds__(256) void gemm_out(
    const float* __restrict__ ct, const float* __restrict__ W,
    float* __restrict__ out)
{
    const int jt = blockIdx.x;
    const int t  = threadIdx.x;
    const int c = t & 15;
    const int r = t >> 4;
    const int lane = t & 63;
    const int w  = t >> 6;           // A (b) subtile
    const int rr = lane & 15;
    const int kg = lane >> 4;

    __shared__ __align__(16) ushort Ch[64][72];   // ct rows (b)
    __shared__ __align__(16) ushort Cl[64][72];
    __shared__ __align__(16) ushort Wh[64][72];   // W rows (j)
    __shared__ __align__(16) ushort Wl[64][72];

    floatx4 acc[4];
#pragma unroll
    for (int js = 0; js < 4; ++js) acc[js] = (floatx4){0.f, 0.f, 0.f, 0.f};

    for (int kk = 0; kk < HH; kk += 64) {
        const int kg4 = kk + 4 * c;
#pragma unroll
        for (int i = 0; i < 4; ++i) {
            const int row = r + 16 * i;
            stage_split(&Ch[0][0], &Cl[0][0], row, 4 * c,
                        *(const float4*)(ct + (size_t)row * HH + kg4));
            stage_split(&Wh[0][0], &Wl[0][0], row, 4 * c,
                        *(const float4*)(W + (size_t)(jt * 64 + row) * HH + kg4));
        }
        __syncthreads();

        const int aoff = (w * 16 + rr) * 72 + kg * 8;
        short8 ah[2], al[2];
        ah[0] = *(const short8*)((const void*)(&Ch[0][0] + aoff));
        ah[1] = *(const short8*)((const void*)(&Ch[0][0] + aoff + 32));
        al[0] = *(const short8*)((const void*)(&Cl[0][0] + aoff));
        al[1] = *(const short8*)((const void*)(&Cl[0][0] + aoff + 32));

#pragma unroll
        for (int js = 0; js < 4; ++js) {
            const int boff = (js * 16 + rr) * 72 + kg * 8;
#pragma unroll
            for (int kh = 0; kh < 2; ++kh) {
                short8 bh = *(const short8*)((const void*)(&Wh[0][0] + boff + kh * 32));
                short8 bl = *(const short8*)((const void*)(&Wl[0][0] + boff + kh * 32));
                acc[js] = MFMA_BF16(ah[kh], bh, acc[js]);
                acc[js] = MFMA_BF16(al[kh], bh, acc[js]);
                acc[js] = MFMA_BF16(ah[kh], bl, acc[js]);
            }
        }
        __syncthreads();
    }

    // D: row = b-within-subtile = kg*4+reg, col = j-within-subtile = rr
#pragma unroll
    for (int js = 0; js < 4; ++js) {
#pragma unroll
        for (int reg = 0; reg < 4; ++reg) {
            const int b = w * 16 + kg * 4 + reg;
            const int j = jt * 64 + js * 16 + rr;
            out[(size_t)b * HH + j] = acc[js][reg];
        }
    }
}

extern "C" void kernel_launch(void* const* d_in, const int* in_sizes, int n_in,
                              void* d_out, int out_size, void* d_ws, size_t ws_size,
                              hipStream_t stream)
{
    const float* encode_h = (const float*)d_in[0];
    const float* x_t      = (const float*)d_in[1];
    const float* h0       = (const float*)d_in[2];
    const float* c0       = (const float*)d_in[3];
    const float* W_ih     = (const float*)d_in[4];
    const float* W_hh     = (const float*)d_in[5];
    const float* b_ih     = (const float*)d_in[6];
    const float* b_hh     = (const float*)d_in[7];
    const float* W_ht2tan = (const float*)d_in[8];
    const float* W_tan2pt = (const float*)d_in[9];
    const float* W_ct2ht  = (const float*)d_in[10];
    const int*   elen     = (const int*)d_in[11];
    float* out = (float*)d_out;

    float* ws = (float*)d_ws;
    float* yt    = ws;                                        // 65536
    float* part2 = yt + (size_t)BB * HH;                      // KS3*1024*64
    float* pbuf  = part2 + (size_t)KS3 * HH * BB;             // 64
    int*   lrbuf = (int*)(pbuf + BB);                         // 128 ints
    float* scbuf = pbuf + BB + 2 * BB;                        // 64*128
    float* ctbuf = scbuf + (size_t)BB * 2 * DD;               // 65536

    // K1: fused gates GEMM + LSTM -> yt (256 blocks)
    gates_lstm<<<256, 256, 0, stream>>>(x_t, h0, W_ih, W_hh, b_ih, b_hh, c0, yt);

    // K2: t1 partials = yt @ W_ht2tan^T, grid (16,4)
    dim3 g2(HH / 64, KS3);
    gemm_mfma<<<g2, 256, 0, stream>>>(yt, HH, W_ht2tan, HH, HH, HH, part2);

    // K3: p + window bounds
    pos_kernel<<<BB, 256, 0, stream>>>(part2, W_tan2pt, elen, pbuf, lrbuf);

    // K4: windowed raw scores, grid (64,8)
    dim3 g4(BB, 8);
    attn_scores<<<g4, 256, 0, stream>>>(encode_h, yt, lrbuf, scbuf);

    // K5: softmax + gauss + ct, grid (64,4), block 512
    dim3 g5(BB, 4);
    attn_ct<<<g5, 512, 0, stream>>>(encode_h, scbuf, pbuf, lrbuf, ctbuf);

    // K6: out = ct @ W_ct2ht^T, direct [b][j] write (16 blocks)
    gemm_out<<<16, 256, 0, stream>>>(ctbuf, W_ct2ht, out);
}

// Round 8
// 125.079 us; speedup vs baseline: 3.8548x; 1.5837x over previous
//
#include <hip/hip_runtime.h>
#include <hip/hip_bf16.h>
#include <math.h>

// Problem constants
#define BB 64
#define SS 2048
#define HH 1024
#define EE 1024
#define DD 64          // window half-size
#define G4H 4096       // 4*H
#define KS1 8          // k-splits for gates GEMM (K=3072, kchunk=384)
#define KS2 16         // k-splits for the t1 (H=1024) GEMM

typedef __attribute__((ext_vector_type(8))) short short8;
typedef __attribute__((ext_vector_type(4))) float floatx4;

#define MFMA_BF16(a, b, c) __builtin_amdgcn_mfma_f32_16x16x32_bf16((a), (b), (c), 0, 0, 0)

__device__ __forceinline__ float sigmoidf_(float x) { return 1.0f / (1.0f + expf(-x)); }

__device__ __forceinline__ ushort f2bf(float f) {
    return __builtin_bit_cast(ushort, __float2bfloat16(f));
}
__device__ __forceinline__ float bf2f(ushort h) {
    return __uint_as_float(((uint)h) << 16);
}

// split float4 into hi/lo bf16 pairs and store to LDS tiles (row stride 72 ushorts = 144 B)
__device__ __forceinline__ void stage_split(ushort* hbase, ushort* lbase, int row, int col, float4 v) {
    const ushort hx = f2bf(v.x), hy = f2bf(v.y), hz = f2bf(v.z), hw = f2bf(v.w);
    const float  lx = v.x - bf2f(hx), ly = v.y - bf2f(hy);
    const float  lz = v.z - bf2f(hz), lw = v.w - bf2f(hw);
    uint2 hp, lp;
    hp.x = (uint)hx | ((uint)hy << 16);
    hp.y = (uint)hz | ((uint)hw << 16);
    lp.x = (uint)f2bf(lx) | ((uint)f2bf(ly) << 16);
    lp.y = (uint)f2bf(lz) | ((uint)f2bf(lw) << 16);
    *(uint2*)(hbase + row * 72 + col) = hp;
    *(uint2*)(lbase + row * 72 + col) = lp;
}

// bf16x3 split-MFMA partial GEMM: part[ks][j][b] = sum_{k in chunk} Xrow(b,k)*Wrow(j,k)
// X/W are each a concat of two row-major matrices along k (split at k1len).
// Tile: 64 j x 64 b x 64 k. 4 waves; wave w owns j-subtile w. grid=(Jtot/64, KS), block=256.
__global__ __launch_bounds__(256) void gemm_mfma(
    const float* __restrict__ X1, int x1ld,
    const float* __restrict__ X2, int x2ld,
    const float* __restrict__ W1, int w1ld,
    const float* __restrict__ W2, int w2ld,
    int k1len, int Ktot, int Jtot,
    float* __restrict__ part)
{
    const int jt = blockIdx.x;
    const int ks = blockIdx.y;
    const int KS = gridDim.y;
    const int kchunk = Ktot / KS;
    const int k0 = ks * kchunk;
    const int t  = threadIdx.x;

    const int c = t & 15;
    const int r = t >> 4;
    const int lane = t & 63;
    const int wj   = t >> 6;
    const int rr   = lane & 15;
    const int kg   = lane >> 4;

    __shared__ __align__(16) ushort Wh[64][72];
    __shared__ __align__(16) ushort Wl[64][72];
    __shared__ __align__(16) ushort Xh[64][72];
    __shared__ __align__(16) ushort Xl[64][72];

    floatx4 acc[4];
#pragma unroll
    for (int bs = 0; bs < 4; ++bs) acc[bs] = (floatx4){0.f, 0.f, 0.f, 0.f};

    for (int kk = k0; kk < k0 + kchunk; kk += 64) {
        const int kg4 = kk + 4 * c;
#pragma unroll
        for (int i = 0; i < 4; ++i) {
            const int row = r + 16 * i;
            const float* xs = (kg4 < k1len) ? (X1 + (size_t)row * x1ld + kg4)
                                            : (X2 + (size_t)row * x2ld + (kg4 - k1len));
            float4 xv = *(const float4*)xs;
            const int j = jt * 64 + row;
            const float* wsrc = (kg4 < k1len) ? (W1 + (size_t)j * w1ld + kg4)
                                              : (W2 + (size_t)j * w2ld + (kg4 - k1len));
            float4 wv = *(const float4*)wsrc;
            stage_split(&Xh[0][0], &Xl[0][0], row, 4 * c, xv);
            stage_split(&Wh[0][0], &Wl[0][0], row, 4 * c, wv);
        }
        __syncthreads();

        const int aoff = (wj * 16 + rr) * 72 + kg * 8;
        short8 ah[2], al[2];
        ah[0] = *(const short8*)((const void*)(&Wh[0][0] + aoff));
        ah[1] = *(const short8*)((const void*)(&Wh[0][0] + aoff + 32));
        al[0] = *(const short8*)((const void*)(&Wl[0][0] + aoff));
        al[1] = *(const short8*)((const void*)(&Wl[0][0] + aoff + 32));

#pragma unroll
        for (int bs = 0; bs < 4; ++bs) {
            const int boff = (bs * 16 + rr) * 72 + kg * 8;
#pragma unroll
            for (int kh = 0; kh < 2; ++kh) {
                short8 bh = *(const short8*)((const void*)(&Xh[0][0] + boff + kh * 32));
                short8 bl = *(const short8*)((const void*)(&Xl[0][0] + boff + kh * 32));
                acc[bs] = MFMA_BF16(ah[kh], bh, acc[bs]);   // hi*hi
                acc[bs] = MFMA_BF16(al[kh], bh, acc[bs]);   // lo*hi
                acc[bs] = MFMA_BF16(ah[kh], bl, acc[bs]);   // hi*lo
            }
        }
        __syncthreads();
    }

    // C/D layout: col = lane&15 (b), row = (lane>>4)*4 + reg (j within subtile)
#pragma unroll
    for (int bs = 0; bs < 4; ++bs) {
#pragma unroll
        for (int reg = 0; reg < 4; ++reg) {
            const int j = jt * 64 + wj * 16 + kg * 4 + reg;
            const int b = bs * 16 + rr;
            part[((size_t)ks * Jtot + j) * BB + b] = acc[bs][reg];
        }
    }
}

// LSTM cell from gate partials. grid = H/4 = 256 blocks, block = 256.
__global__ __launch_bounds__(256) void lstm_cell(
    const float* __restrict__ part,
    const float* __restrict__ b_ih, const float* __restrict__ b_hh,
    const float* __restrict__ c0, float* __restrict__ yt)
{
    const int t = threadIdx.x;
    const int b = t & 63;
    const int h = blockIdx.x * 4 + (t >> 6);

    float g4[4];
#pragma unroll
    for (int q = 0; q < 4; ++q) {
        const int j = h + q * HH;
        float s = b_ih[j] + b_hh[j];
#pragma unroll
        for (int ks = 0; ks < KS1; ++ks)
            s += part[((size_t)ks * G4H + j) * BB + b];
        g4[q] = s;
    }
    const float ig = sigmoidf_(g4[0]);
    const float fg = sigmoidf_(g4[1]);
    const float gg = tanhf(g4[2]);
    const float og = sigmoidf_(g4[3]);
    const float c  = fg * c0[(size_t)b * HH + h] + ig * gg;
    yt[(size_t)b * HH + h] = og * tanhf(c);
}

// p_t = len * sigmoid( sum_i tanh(t1[b][i]) * v[i] ); window bounds.
// grid = B, block = 256. part2[ks][i][b]
__global__ __launch_bounds__(256) void pos_kernel(
    const float* __restrict__ part2, const float* __restrict__ v,
    const int* __restrict__ elen,
    float* __restrict__ p_out, int* __restrict__ lr_out)
{
    const int b = blockIdx.x;
    const int t = threadIdx.x;
    float acc = 0.0f;
    for (int i = t; i < HH; i += 256) {
        float s = 0.0f;
#pragma unroll
        for (int ks = 0; ks < KS2; ++ks)
            s += part2[((size_t)ks * HH + i) * BB + b];
        acc += tanhf(s) * v[i];
    }
    __shared__ float red[256];
    red[t] = acc;
    __syncthreads();
    if (t < 128) red[t] += red[t + 128];
    __syncthreads();
    if (t < 64) {
        float x = red[t] + red[t + 64];
#pragma unroll
        for (int off = 32; off; off >>= 1) x += __shfl_xor(x, off);
        if (t == 0) {
            const float pt  = sigmoidf_(x);
            const float len = (float)elen[b];
            const float p   = len * pt;
            const int   pf  = (int)floorf(p);
            const int   left  = max(0, pf - DD);
            const int   right = min(elen[b], pf + DD);
            p_out[b] = p;
            lr_out[b * 2 + 0] = left;
            lr_out[b * 2 + 1] = right;
        }
    }
}

// Windowed raw scores. grid = (B, 8), block = 256 (4 waves, 4 si each).
// Writes sc[b][0..128) with -1e30 padding beyond window.
__global__ __launch_bounds__(256) void attn_scores(
    const float* __restrict__ encode_h, const float* __restrict__ yt,
    const int* __restrict__ lr, float* __restrict__ sc_out)
{
    const int b = blockIdx.x;
    const int q = blockIdx.y;
    const int t = threadIdx.x;
    const int lane = t & 63;
    const int wv = t >> 6;

    __shared__ float yts[HH];
    *(float4*)&yts[t * 4] = *(const float4*)&yt[(size_t)b * HH + t * 4];
    const int left = lr[b * 2], right = lr[b * 2 + 1];
    const int wsize = right - left;
    __syncthreads();

#pragma unroll
    for (int rr = 0; rr < 4; ++rr) {
        const int si = q * 16 + wv * 4 + rr;
        float s = -1e30f;
        if (si < wsize) {
            const float* eh = encode_h + ((size_t)b * SS + (left + si)) * HH;
            s = 0.0f;
#pragma unroll
            for (int cc = 0; cc < 4; ++cc) {
                const int hb = cc * 256 + lane * 4;
                float4 e = *(const float4*)(eh + hb);
                s += e.x * yts[hb] + e.y * yts[hb + 1] + e.z * yts[hb + 2] + e.w * yts[hb + 3];
            }
#pragma unroll
            for (int off = 32; off; off >>= 1) s += __shfl_xor(s, off);
        }
        if (lane == 0) sc_out[b * 2 * DD + si] = s;
    }
}

// Fused softmax+gauss+ct: grid = (B, 4), block = 512; half-split over si.
__global__ __launch_bounds__(512) void attn_ct(
    const float* __restrict__ encode_h, const float* __restrict__ sc,
    const float* __restrict__ p_buf, const int* __restrict__ lr,
    float* __restrict__ ct)
{
    const int b = blockIdx.x;
    const int t = threadIdx.x;
    const int lane = t & 63;
    const int hh = t & 255;
    const int half = t >> 8;
    const int h = blockIdx.y * 256 + hh;

    __shared__ float scs[2 * DD];
    __shared__ float ats[2 * DD];
    __shared__ float red[256];

    const int left = lr[b * 2];
    if (t < 2 * DD) scs[t] = sc[b * 2 * DD + t];
    __syncthreads();

    float m = fmaxf(scs[lane], scs[lane + 64]);
#pragma unroll
    for (int off = 32; off; off >>= 1) m = fmaxf(m, __shfl_xor(m, off));
    float ssum = expf(scs[lane] - m) + expf(scs[lane + 64] - m);
#pragma unroll
    for (int off = 32; off; off >>= 1) ssum += __shfl_xor(ssum, off);
    const float inv = 1.0f / ssum;

    if (t < 2 * DD) {
        const float dj = (float)(left + t) - p_buf[b];
        ats[t] = expf(scs[t] - m) * inv * expf(-(dj * dj) * (1.0f / 2048.0f));
    }
    __syncthreads();

    const float* ehb = encode_h + ((size_t)b * SS + left + half * 64) * HH + h;
    const float* atp = &ats[half * 64];
    float a0 = 0, a1 = 0, a2 = 0, a3 = 0, a4 = 0, a5 = 0, a6 = 0, a7 = 0;
#pragma unroll 2
    for (int si = 0; si < 64; si += 8) {
        a0 = fmaf(atp[si + 0], ehb[(size_t)(si + 0) * HH], a0);
        a1 = fmaf(atp[si + 1], ehb[(size_t)(si + 1) * HH], a1);
        a2 = fmaf(atp[si + 2], ehb[(size_t)(si + 2) * HH], a2);
        a3 = fmaf(atp[si + 3], ehb[(size_t)(si + 3) * HH], a3);
        a4 = fmaf(atp[si + 4], ehb[(size_t)(si + 4) * HH], a4);
        a5 = fmaf(atp[si + 5], ehb[(size_t)(si + 5) * HH], a5);
        a6 = fmaf(atp[si + 6], ehb[(size_t)(si + 6) * HH], a6);
        a7 = fmaf(atp[si + 7], ehb[(size_t)(si + 7) * HH], a7);
    }
    const float a = ((a0 + a1) + (a2 + a3)) + ((a4 + a5) + (a6 + a7));

    if (half == 1) red[hh] = a;
    __syncthreads();
    if (half == 0) ct[(size_t)b * HH + h] = a + red[hh];
}

// Final GEMM with swapped roles: out[b][j] = sum_k ct[b][k]*W[j][k], direct [b][j] write.
// A-operand = ct rows (b), B-operand = W rows (j). grid = 16 (j-tiles of 64), full K.
__global__ __launch_bounds__(256) void gemm_out(
    const float* __restrict__ ct, const float* __restrict__ W,
    float* __restrict__ out)
{
    const int jt = blockIdx.x;
    const int t  = threadIdx.x;
    const int c = t & 15;
    const int r = t >> 4;
    const int lane = t & 63;
    const int w  = t >> 6;           // A (b) subtile
    const int rr = lane & 15;
    const int kg = lane >> 4;

    __shared__ __align__(16) ushort Ch[64][72];   // ct rows (b)
    __shared__ __align__(16) ushort Cl[64][72];
    __shared__ __align__(16) ushort Wh[64][72];   // W rows (j)
    __shared__ __align__(16) ushort Wl[64][72];

    floatx4 acc[4];
#pragma unroll
    for (int js = 0; js < 4; ++js) acc[js] = (floatx4){0.f, 0.f, 0.f, 0.f};

    for (int kk = 0; kk < HH; kk += 64) {
        const int kg4 = kk + 4 * c;
#pragma unroll
        for (int i = 0; i < 4; ++i) {
            const int row = r + 16 * i;
            stage_split(&Ch[0][0], &Cl[0][0], row, 4 * c,
                        *(const float4*)(ct + (size_t)row * HH + kg4));
            stage_split(&Wh[0][0], &Wl[0][0], row, 4 * c,
                        *(const float4*)(W + (size_t)(jt * 64 + row) * HH + kg4));
        }
        __syncthreads();

        const int aoff = (w * 16 + rr) * 72 + kg * 8;
        short8 ah[2], al[2];
        ah[0] = *(const short8*)((const void*)(&Ch[0][0] + aoff));
        ah[1] = *(const short8*)((const void*)(&Ch[0][0] + aoff + 32));
        al[0] = *(const short8*)((const void*)(&Cl[0][0] + aoff));
        al[1] = *(const short8*)((const void*)(&Cl[0][0] + aoff + 32));

#pragma unroll
        for (int js = 0; js < 4; ++js) {
            const int boff = (js * 16 + rr) * 72 + kg * 8;
#pragma unroll
            for (int kh = 0; kh < 2; ++kh) {
                short8 bh = *(const short8*)((const void*)(&Wh[0][0] + boff + kh * 32));
                short8 bl = *(const short8*)((const void*)(&Wl[0][0] + boff + kh * 32));
                acc[js] = MFMA_BF16(ah[kh], bh, acc[js]);
                acc[js] = MFMA_BF16(al[kh], bh, acc[js]);
                acc[js] = MFMA_BF16(ah[kh], bl, acc[js]);
            }
        }
        __syncthreads();
    }

    // D: row = b-within-subtile = kg*4+reg, col = j-within-subtile = rr
#pragma unroll
    for (int js = 0; js < 4; ++js) {
#pragma unroll
        for (int reg = 0; reg < 4; ++reg) {
            const int b = w * 16 + kg * 4 + reg;
            const int j = jt * 64 + js * 16 + rr;
            out[(size_t)b * HH + j] = acc[js][reg];
        }
    }
}

extern "C" void kernel_launch(void* const* d_in, const int* in_sizes, int n_in,
                              void* d_out, int out_size, void* d_ws, size_t ws_size,
                              hipStream_t stream)
{
    const float* encode_h = (const float*)d_in[0];
    const float* x_t      = (const float*)d_in[1];
    const float* h0       = (const float*)d_in[2];
    const float* c0       = (const float*)d_in[3];
    const float* W_ih     = (const float*)d_in[4];
    const float* W_hh     = (const float*)d_in[5];
    const float* b_ih     = (const float*)d_in[6];
    const float* b_hh     = (const float*)d_in[7];
    const float* W_ht2tan = (const float*)d_in[8];
    const float* W_tan2pt = (const float*)d_in[9];
    const float* W_ct2ht  = (const float*)d_in[10];
    const int*   elen     = (const int*)d_in[11];
    float* out = (float*)d_out;

    float* ws = (float*)d_ws;
    float* gates_part = ws;                                   // KS1*4096*64 = 2M
    float* yt    = gates_part + (size_t)KS1 * G4H * BB;       // 65536
    float* part2 = yt + (size_t)BB * HH;                      // KS2*1024*64 = 1M
    float* pbuf  = part2 + (size_t)KS2 * HH * BB;             // 64
    int*   lrbuf = (int*)(pbuf + BB);                         // 128 ints
    float* scbuf = pbuf + BB + 2 * BB;                        // 64*128
    float* ctbuf = scbuf + (size_t)BB * 2 * DD;               // 65536

    // K1: gates partial GEMM (K = 2048 | 1024 concat), grid (64,8) = 512 blocks
    dim3 g1(G4H / 64, KS1);
    gemm_mfma<<<g1, 256, 0, stream>>>(x_t, EE + HH, h0, HH,
                                      W_ih, EE + HH, W_hh, HH,
                                      2048, 3072, G4H, gates_part);
    // K2: LSTM cell -> yt
    lstm_cell<<<HH / 4, 256, 0, stream>>>(gates_part, b_ih, b_hh, c0, yt);

    // K3a: t1 = yt @ W_ht2tan^T (partials), grid (16,16) = 256 blocks
    dim3 g3(HH / 64, KS2);
    gemm_mfma<<<g3, 256, 0, stream>>>(yt, HH, yt, HH,
                                      W_ht2tan, HH, W_ht2tan, HH,
                                      HH, HH, HH, part2);
    // K3b: p, window bounds
    pos_kernel<<<BB, 256, 0, stream>>>(part2, W_tan2pt, elen, pbuf, lrbuf);

    // K4a: windowed raw scores, grid (64,8) = 512 blocks
    dim3 g4a(BB, 8);
    attn_scores<<<g4a, 256, 0, stream>>>(encode_h, yt, lrbuf, scbuf);
    // K4b: softmax + gauss + ct, grid (64,4), block 512
    dim3 g4b(BB, 4);
    attn_ct<<<g4b, 512, 0, stream>>>(encode_h, scbuf, pbuf, lrbuf, ctbuf);

    // K5: out = ct @ W_ct2ht^T, direct [b][j] write (16 blocks)
    gemm_out<<<16, 256, 0, stream>>>(ctbuf, W_ct2ht, out);
}

// Round 9
// 77.593 us; speedup vs baseline: 6.2138x; 1.6120x over previous
//
#include <hip/hip_runtime.h>
#include <hip/hip_bf16.h>
#include <math.h>

// Problem constants
#define BB 64
#define SS 2048
#define HH 1024
#define EE 1024
#define DD 64          // window half-size
#define G4H 4096       // 4*H
#define KS1 8          // k-splits for gates GEMM (K=3072, kchunk=384)
#define KS2 16         // k-splits for the H=1024 GEMMs (kchunk=64)

typedef __attribute__((ext_vector_type(8))) short short8;
typedef __attribute__((ext_vector_type(4))) float floatx4;

#define MFMA_BF16(a, b, c) __builtin_amdgcn_mfma_f32_16x16x32_bf16((a), (b), (c), 0, 0, 0)

__device__ __forceinline__ float sigmoidf_(float x) { return 1.0f / (1.0f + expf(-x)); }

__device__ __forceinline__ ushort f2bf(float f) {
    return __builtin_bit_cast(ushort, __float2bfloat16(f));
}
__device__ __forceinline__ float bf2f(ushort h) {
    return __uint_as_float(((uint)h) << 16);
}

// split float4 into hi/lo bf16 pairs and store to LDS tiles (row stride 72 ushorts = 144 B)
__device__ __forceinline__ void stage_split(ushort* hbase, ushort* lbase, int row, int col, float4 v) {
    const ushort hx = f2bf(v.x), hy = f2bf(v.y), hz = f2bf(v.z), hw = f2bf(v.w);
    const float  lx = v.x - bf2f(hx), ly = v.y - bf2f(hy);
    const float  lz = v.z - bf2f(hz), lw = v.w - bf2f(hw);
    uint2 hp, lp;
    hp.x = (uint)hx | ((uint)hy << 16);
    hp.y = (uint)hz | ((uint)hw << 16);
    lp.x = (uint)f2bf(lx) | ((uint)f2bf(ly) << 16);
    lp.y = (uint)f2bf(lz) | ((uint)f2bf(lw) << 16);
    *(uint2*)(hbase + row * 72 + col) = hp;
    *(uint2*)(lbase + row * 72 + col) = lp;
}

// bf16x3 split-MFMA partial GEMM: part[ks][j][b] = sum_{k in chunk} Xrow(b,k)*Wrow(j,k)
// X/W are each a concat of two row-major matrices along k (split at k1len).
// Tile: 64 j x 64 b x 64 k. 4 waves; wave w owns j-subtile w. grid=(Jtot/64, KS), block=256.
__global__ __launch_bounds__(256) void gemm_mfma(
    const float* __restrict__ X1, int x1ld,
    const float* __restrict__ X2, int x2ld,
    const float* __restrict__ W1, int w1ld,
    const float* __restrict__ W2, int w2ld,
    int k1len, int Ktot, int Jtot,
    float* __restrict__ part)
{
    const int jt = blockIdx.x;
    const int ks = blockIdx.y;
    const int KS = gridDim.y;
    const int kchunk = Ktot / KS;
    const int k0 = ks * kchunk;
    const int t  = threadIdx.x;

    const int c = t & 15;
    const int r = t >> 4;
    const int lane = t & 63;
    const int wj   = t >> 6;
    const int rr   = lane & 15;
    const int kg   = lane >> 4;

    __shared__ __align__(16) ushort Wh[64][72];
    __shared__ __align__(16) ushort Wl[64][72];
    __shared__ __align__(16) ushort Xh[64][72];
    __shared__ __align__(16) ushort Xl[64][72];

    floatx4 acc[4];
#pragma unroll
    for (int bs = 0; bs < 4; ++bs) acc[bs] = (floatx4){0.f, 0.f, 0.f, 0.f};

    for (int kk = k0; kk < k0 + kchunk; kk += 64) {
        const int kg4 = kk + 4 * c;
#pragma unroll
        for (int i = 0; i < 4; ++i) {
            const int row = r + 16 * i;
            const float* xs = (kg4 < k1len) ? (X1 + (size_t)row * x1ld + kg4)
                                            : (X2 + (size_t)row * x2ld + (kg4 - k1len));
            float4 xv = *(const float4*)xs;
            const int j = jt * 64 + row;
            const float* wsrc = (kg4 < k1len) ? (W1 + (size_t)j * w1ld + kg4)
                                              : (W2 + (size_t)j * w2ld + (kg4 - k1len));
            float4 wv = *(const float4*)wsrc;
            stage_split(&Xh[0][0], &Xl[0][0], row, 4 * c, xv);
            stage_split(&Wh[0][0], &Wl[0][0], row, 4 * c, wv);
        }
        __syncthreads();

        const int aoff = (wj * 16 + rr) * 72 + kg * 8;
        short8 ah[2], al[2];
        ah[0] = *(const short8*)((const void*)(&Wh[0][0] + aoff));
        ah[1] = *(const short8*)((const void*)(&Wh[0][0] + aoff + 32));
        al[0] = *(const short8*)((const void*)(&Wl[0][0] + aoff));
        al[1] = *(const short8*)((const void*)(&Wl[0][0] + aoff + 32));

#pragma unroll
        for (int bs = 0; bs < 4; ++bs) {
            const int boff = (bs * 16 + rr) * 72 + kg * 8;
#pragma unroll
            for (int kh = 0; kh < 2; ++kh) {
                short8 bh = *(const short8*)((const void*)(&Xh[0][0] + boff + kh * 32));
                short8 bl = *(const short8*)((const void*)(&Xl[0][0] + boff + kh * 32));
                acc[bs] = MFMA_BF16(ah[kh], bh, acc[bs]);   // hi*hi
                acc[bs] = MFMA_BF16(al[kh], bh, acc[bs]);   // lo*hi
                acc[bs] = MFMA_BF16(ah[kh], bl, acc[bs]);   // hi*lo
            }
        }
        __syncthreads();
    }

    // C/D layout: col = lane&15 (b), row = (lane>>4)*4 + reg (j within subtile)
#pragma unroll
    for (int bs = 0; bs < 4; ++bs) {
#pragma unroll
        for (int reg = 0; reg < 4; ++reg) {
            const int j = jt * 64 + wj * 16 + kg * 4 + reg;
            const int b = bs * 16 + rr;
            part[((size_t)ks * Jtot + j) * BB + b] = acc[bs][reg];
        }
    }
}

// LSTM cell from gate partials. grid = H/4 = 256 blocks, block = 256.
__global__ __launch_bounds__(256) void lstm_cell(
    const float* __restrict__ part,
    const float* __restrict__ b_ih, const float* __restrict__ b_hh,
    const float* __restrict__ c0, float* __restrict__ yt)
{
    const int t = threadIdx.x;
    const int b = t & 63;
    const int h = blockIdx.x * 4 + (t >> 6);

    float g4[4];
#pragma unroll
    for (int q = 0; q < 4; ++q) {
        const int j = h + q * HH;
        float s = b_ih[j] + b_hh[j];
#pragma unroll
        for (int ks = 0; ks < KS1; ++ks)
            s += part[((size_t)ks * G4H + j) * BB + b];
        g4[q] = s;
    }
    const float ig = sigmoidf_(g4[0]);
    const float fg = sigmoidf_(g4[1]);
    const float gg = tanhf(g4[2]);
    const float og = sigmoidf_(g4[3]);
    const float c  = fg * c0[(size_t)b * HH + h] + ig * gg;
    yt[(size_t)b * HH + h] = og * tanhf(c);
}

// p_t = len * sigmoid( sum_i tanh(t1[b][i]) * v[i] ); window bounds.
// grid = B, block = 256. part2[ks][i][b]
__global__ __launch_bounds__(256) void pos_kernel(
    const float* __restrict__ part2, const float* __restrict__ v,
    const int* __restrict__ elen,
    float* __restrict__ p_out, int* __restrict__ lr_out)
{
    const int b = blockIdx.x;
    const int t = threadIdx.x;
    float acc = 0.0f;
    for (int i = t; i < HH; i += 256) {
        float s = 0.0f;
#pragma unroll
        for (int ks = 0; ks < KS2; ++ks)
            s += part2[((size_t)ks * HH + i) * BB + b];
        acc += tanhf(s) * v[i];
    }
    __shared__ float red[256];
    red[t] = acc;
    __syncthreads();
    if (t < 128) red[t] += red[t + 128];
    __syncthreads();
    if (t < 64) {
        float x = red[t] + red[t + 64];
#pragma unroll
        for (int off = 32; off; off >>= 1) x += __shfl_xor(x, off);
        if (t == 0) {
            const float pt  = sigmoidf_(x);
            const float len = (float)elen[b];
            const float p   = len * pt;
            const int   pf  = (int)floorf(p);
            const int   left  = max(0, pf - DD);
            const int   right = min(elen[b], pf + DD);
            p_out[b] = p;
            lr_out[b * 2 + 0] = left;
            lr_out[b * 2 + 1] = right;
        }
    }
}

// Windowed raw scores. grid = (B, 16), block = 256 (4 waves, 2 si each).
// Writes sc[b][0..128) with -1e30 padding beyond window.
__global__ __launch_bounds__(256) void attn_scores(
    const float* __restrict__ encode_h, const float* __restrict__ yt,
    const int* __restrict__ lr, float* __restrict__ sc_out)
{
    const int b = blockIdx.x;
    const int q = blockIdx.y;
    const int t = threadIdx.x;
    const int lane = t & 63;
    const int wv = t >> 6;

    __shared__ float yts[HH];
    *(float4*)&yts[t * 4] = *(const float4*)&yt[(size_t)b * HH + t * 4];
    const int left = lr[b * 2], right = lr[b * 2 + 1];
    const int wsize = right - left;
    __syncthreads();

#pragma unroll
    for (int rr = 0; rr < 2; ++rr) {
        const int si = q * 8 + wv * 2 + rr;
        float s = -1e30f;
        if (si < wsize) {
            const float* eh = encode_h + ((size_t)b * SS + (left + si)) * HH;
            s = 0.0f;
#pragma unroll
            for (int cc = 0; cc < 4; ++cc) {
                const int hb = cc * 256 + lane * 4;
                float4 e = *(const float4*)(eh + hb);
                s += e.x * yts[hb] + e.y * yts[hb + 1] + e.z * yts[hb + 2] + e.w * yts[hb + 3];
            }
#pragma unroll
            for (int off = 32; off; off >>= 1) s += __shfl_xor(s, off);
        }
        if (lane == 0) sc_out[b * 2 * DD + si] = s;
    }
}

// Fused softmax+gauss+ct: grid = (B, 4), block = 512; half-split over si.
__global__ __launch_bounds__(512) void attn_ct(
    const float* __restrict__ encode_h, const float* __restrict__ sc,
    const float* __restrict__ p_buf, const int* __restrict__ lr,
    float* __restrict__ ct)
{
    const int b = blockIdx.x;
    const int t = threadIdx.x;
    const int lane = t & 63;
    const int hh = t & 255;
    const int half = t >> 8;
    const int h = blockIdx.y * 256 + hh;

    __shared__ float scs[2 * DD];
    __shared__ float ats[2 * DD];
    __shared__ float red[256];

    const int left = lr[b * 2];
    if (t < 2 * DD) scs[t] = sc[b * 2 * DD + t];
    __syncthreads();

    float m = fmaxf(scs[lane], scs[lane + 64]);
#pragma unroll
    for (int off = 32; off; off >>= 1) m = fmaxf(m, __shfl_xor(m, off));
    float ssum = expf(scs[lane] - m) + expf(scs[lane + 64] - m);
#pragma unroll
    for (int off = 32; off; off >>= 1) ssum += __shfl_xor(ssum, off);
    const float inv = 1.0f / ssum;

    if (t < 2 * DD) {
        const float dj = (float)(left + t) - p_buf[b];
        ats[t] = expf(scs[t] - m) * inv * expf(-(dj * dj) * (1.0f / 2048.0f));
    }
    __syncthreads();

    const float* ehb = encode_h + ((size_t)b * SS + left + half * 64) * HH + h;
    const float* atp = &ats[half * 64];
    float a0 = 0, a1 = 0, a2 = 0, a3 = 0, a4 = 0, a5 = 0, a6 = 0, a7 = 0;
#pragma unroll 2
    for (int si = 0; si < 64; si += 8) {
        a0 = fmaf(atp[si + 0], ehb[(size_t)(si + 0) * HH], a0);
        a1 = fmaf(atp[si + 1], ehb[(size_t)(si + 1) * HH], a1);
        a2 = fmaf(atp[si + 2], ehb[(size_t)(si + 2) * HH], a2);
        a3 = fmaf(atp[si + 3], ehb[(size_t)(si + 3) * HH], a3);
        a4 = fmaf(atp[si + 4], ehb[(size_t)(si + 4) * HH], a4);
        a5 = fmaf(atp[si + 5], ehb[(size_t)(si + 5) * HH], a5);
        a6 = fmaf(atp[si + 6], ehb[(size_t)(si + 6) * HH], a6);
        a7 = fmaf(atp[si + 7], ehb[(size_t)(si + 7) * HH], a7);
    }
    const float a = ((a0 + a1) + (a2 + a3)) + ((a4 + a5) + (a6 + a7));

    if (half == 1) red[hh] = a;
    __syncthreads();
    if (half == 0) ct[(size_t)b * HH + h] = a + red[hh];
}

// out[b][j] = sum_ks part3[ks][j][b].  grid = H/4 = 256, block = 256 (coalesced reads).
__global__ __launch_bounds__(256) void reduce_out(
    const float* __restrict__ part3, float* __restrict__ out)
{
    const int t = threadIdx.x;
    const int b = t & 63;
    const int j = blockIdx.x * 4 + (t >> 6);
    float s = 0.0f;
#pragma unroll
    for (int ks = 0; ks < KS2; ++ks)
        s += part3[((size_t)ks * HH + j) * BB + b];
    out[(size_t)b * HH + j] = s;
}

extern "C" void kernel_launch(void* const* d_in, const int* in_sizes, int n_in,
                              void* d_out, int out_size, void* d_ws, size_t ws_size,
                              hipStream_t stream)
{
    const float* encode_h = (const float*)d_in[0];
    const float* x_t      = (const float*)d_in[1];
    const float* h0       = (const float*)d_in[2];
    const float* c0       = (const float*)d_in[3];
    const float* W_ih     = (const float*)d_in[4];
    const float* W_hh     = (const float*)d_in[5];
    const float* b_ih     = (const float*)d_in[6];
    const float* b_hh     = (const float*)d_in[7];
    const float* W_ht2tan = (const float*)d_in[8];
    const float* W_tan2pt = (const float*)d_in[9];
    const float* W_ct2ht  = (const float*)d_in[10];
    const int*   elen     = (const int*)d_in[11];
    float* out = (float*)d_out;

    float* ws = (float*)d_ws;
    float* gates_part = ws;                                   // KS1*4096*64 = 2M
    float* yt    = gates_part + (size_t)KS1 * G4H * BB;       // 65536
    float* part2 = yt + (size_t)BB * HH;                      // KS2*1024*64 = 1M
    float* pbuf  = part2 + (size_t)KS2 * HH * BB;             // 64
    int*   lrbuf = (int*)(pbuf + BB);                         // 128 ints
    float* scbuf = pbuf + BB + 2 * BB;                        // 64*128
    float* ctbuf = scbuf + (size_t)BB * 2 * DD;               // 65536
    float* part3 = ctbuf + (size_t)BB * HH;                   // KS2*1024*64 = 1M

    // K1: gates partial GEMM (K = 2048 | 1024 concat), grid (64,8) = 512 blocks
    dim3 g1(G4H / 64, KS1);
    gemm_mfma<<<g1, 256, 0, stream>>>(x_t, EE + HH, h0, HH,
                                      W_ih, EE + HH, W_hh, HH,
                                      2048, 3072, G4H, gates_part);
    // K2: LSTM cell -> yt
    lstm_cell<<<HH / 4, 256, 0, stream>>>(gates_part, b_ih, b_hh, c0, yt);

    // K3a: t1 = yt @ W_ht2tan^T (partials), grid (16,16) = 256 blocks
    dim3 g3(HH / 64, KS2);
    gemm_mfma<<<g3, 256, 0, stream>>>(yt, HH, yt, HH,
                                      W_ht2tan, HH, W_ht2tan, HH,
                                      HH, HH, HH, part2);
    // K3b: p, window bounds
    pos_kernel<<<BB, 256, 0, stream>>>(part2, W_tan2pt, elen, pbuf, lrbuf);

    // K4a: windowed raw scores, grid (64,16) = 1024 blocks (2 si per wave)
    dim3 g4a(BB, 16);
    attn_scores<<<g4a, 256, 0, stream>>>(encode_h, yt, lrbuf, scbuf);
    // K4b: softmax + gauss + ct, grid (64,4), block 512
    dim3 g4b(BB, 4);
    attn_ct<<<g4b, 512, 0, stream>>>(encode_h, scbuf, pbuf, lrbuf, ctbuf);

    // K5: ht partials = ct @ W_ct2ht^T, grid (16,16)
    gemm_mfma<<<g3, 256, 0, stream>>>(ctbuf, HH, ctbuf, HH,
                                      W_ct2ht, HH, W_ct2ht, HH,
                                      HH, HH, HH, part3);
    // K6: reduce -> out
    reduce_out<<<HH / 4, 256, 0, stream>>>(part3, out);
}

// Round 10
// 74.394 us; speedup vs baseline: 6.4810x; 1.0430x over previous
//
#include <hip/hip_runtime.h>
#include <hip/hip_bf16.h>
#include <math.h>

// Problem constants
#define BB 64
#define SS 2048
#define HH 1024
#define EE 1024
#define DD 64          // window half-size
#define G4H 4096       // 4*H
#define KS1 16         // k-splits for gates GEMM (K=3072, kchunk=192) -> 1024 blocks, 4/CU
#define KS2 16         // k-splits for the H=1024 GEMMs (kchunk=64)

typedef __attribute__((ext_vector_type(8))) short short8;
typedef __attribute__((ext_vector_type(4))) float floatx4;

#define MFMA_BF16(a, b, c) __builtin_amdgcn_mfma_f32_16x16x32_bf16((a), (b), (c), 0, 0, 0)

__device__ __forceinline__ float sigmoidf_(float x) { return 1.0f / (1.0f + expf(-x)); }

__device__ __forceinline__ ushort f2bf(float f) {
    return __builtin_bit_cast(ushort, __float2bfloat16(f));
}
__device__ __forceinline__ float bf2f(ushort h) {
    return __uint_as_float(((uint)h) << 16);
}

// split float4 into hi/lo bf16 pairs and store to LDS tiles (row stride 72 ushorts = 144 B)
__device__ __forceinline__ void stage_split(ushort* hbase, ushort* lbase, int row, int col, float4 v) {
    const ushort hx = f2bf(v.x), hy = f2bf(v.y), hz = f2bf(v.z), hw = f2bf(v.w);
    const float  lx = v.x - bf2f(hx), ly = v.y - bf2f(hy);
    const float  lz = v.z - bf2f(hz), lw = v.w - bf2f(hw);
    uint2 hp, lp;
    hp.x = (uint)hx | ((uint)hy << 16);
    hp.y = (uint)hz | ((uint)hw << 16);
    lp.x = (uint)f2bf(lx) | ((uint)f2bf(ly) << 16);
    lp.y = (uint)f2bf(lz) | ((uint)f2bf(lw) << 16);
    *(uint2*)(hbase + row * 72 + col) = hp;
    *(uint2*)(lbase + row * 72 + col) = lp;
}

// bf16x3 split-MFMA partial GEMM: part[ks][j][b] = sum_{k in chunk} Xrow(b,k)*Wrow(j,k)
// X/W are each a concat of two row-major matrices along k (split at k1len).
// Tile: 64 j x 64 b x 64 k. 4 waves; wave w owns j-subtile w. grid=(Jtot/64, KS), block=256.
__global__ __launch_bounds__(256) void gemm_mfma(
    const float* __restrict__ X1, int x1ld,
    const float* __restrict__ X2, int x2ld,
    const float* __restrict__ W1, int w1ld,
    const float* __restrict__ W2, int w2ld,
    int k1len, int Ktot, int Jtot,
    float* __restrict__ part)
{
    const int jt = blockIdx.x;
    const int ks = blockIdx.y;
    const int KS = gridDim.y;
    const int kchunk = Ktot / KS;
    const int k0 = ks * kchunk;
    const int t  = threadIdx.x;

    const int c = t & 15;
    const int r = t >> 4;
    const int lane = t & 63;
    const int wj   = t >> 6;
    const int rr   = lane & 15;
    const int kg   = lane >> 4;

    __shared__ __align__(16) ushort Wh[64][72];
    __shared__ __align__(16) ushort Wl[64][72];
    __shared__ __align__(16) ushort Xh[64][72];
    __shared__ __align__(16) ushort Xl[64][72];

    floatx4 acc[4];
#pragma unroll
    for (int bs = 0; bs < 4; ++bs) acc[bs] = (floatx4){0.f, 0.f, 0.f, 0.f};

    for (int kk = k0; kk < k0 + kchunk; kk += 64) {
        const int kg4 = kk + 4 * c;
#pragma unroll
        for (int i = 0; i < 4; ++i) {
            const int row = r + 16 * i;
            const float* xs = (kg4 < k1len) ? (X1 + (size_t)row * x1ld + kg4)
                                            : (X2 + (size_t)row * x2ld + (kg4 - k1len));
            float4 xv = *(const float4*)xs;
            const int j = jt * 64 + row;
            const float* wsrc = (kg4 < k1len) ? (W1 + (size_t)j * w1ld + kg4)
                                              : (W2 + (size_t)j * w2ld + (kg4 - k1len));
            float4 wv = *(const float4*)wsrc;
            stage_split(&Xh[0][0], &Xl[0][0], row, 4 * c, xv);
            stage_split(&Wh[0][0], &Wl[0][0], row, 4 * c, wv);
        }
        __syncthreads();

        const int aoff = (wj * 16 + rr) * 72 + kg * 8;
        short8 ah[2], al[2];
        ah[0] = *(const short8*)((const void*)(&Wh[0][0] + aoff));
        ah[1] = *(const short8*)((const void*)(&Wh[0][0] + aoff + 32));
        al[0] = *(const short8*)((const void*)(&Wl[0][0] + aoff));
        al[1] = *(const short8*)((const void*)(&Wl[0][0] + aoff + 32));

#pragma unroll
        for (int bs = 0; bs < 4; ++bs) {
            const int boff = (bs * 16 + rr) * 72 + kg * 8;
#pragma unroll
            for (int kh = 0; kh < 2; ++kh) {
                short8 bh = *(const short8*)((const void*)(&Xh[0][0] + boff + kh * 32));
                short8 bl = *(const short8*)((const void*)(&Xl[0][0] + boff + kh * 32));
                acc[bs] = MFMA_BF16(ah[kh], bh, acc[bs]);   // hi*hi
                acc[bs] = MFMA_BF16(al[kh], bh, acc[bs]);   // lo*hi
                acc[bs] = MFMA_BF16(ah[kh], bl, acc[bs]);   // hi*lo
            }
        }
        __syncthreads();
    }

    // C/D layout: col = lane&15 (b), row = (lane>>4)*4 + reg (j within subtile)
#pragma unroll
    for (int bs = 0; bs < 4; ++bs) {
#pragma unroll
        for (int reg = 0; reg < 4; ++reg) {
            const int j = jt * 64 + wj * 16 + kg * 4 + reg;
            const int b = bs * 16 + rr;
            part[((size_t)ks * Jtot + j) * BB + b] = acc[bs][reg];
        }
    }
}

// LSTM cell from gate partials. grid = H/4 = 256 blocks, block = 256.
__global__ __launch_bounds__(256) void lstm_cell(
    const float* __restrict__ part,
    const float* __restrict__ b_ih, const float* __restrict__ b_hh,
    const float* __restrict__ c0, float* __restrict__ yt)
{
    const int t = threadIdx.x;
    const int b = t & 63;
    const int h = blockIdx.x * 4 + (t >> 6);

    float g4[4];
#pragma unroll
    for (int q = 0; q < 4; ++q) {
        const int j = h + q * HH;
        float s = b_ih[j] + b_hh[j];
#pragma unroll
        for (int ks = 0; ks < KS1; ++ks)
            s += part[((size_t)ks * G4H + j) * BB + b];
        g4[q] = s;
    }
    const float ig = sigmoidf_(g4[0]);
    const float fg = sigmoidf_(g4[1]);
    const float gg = tanhf(g4[2]);
    const float og = sigmoidf_(g4[3]);
    const float c  = fg * c0[(size_t)b * HH + h] + ig * gg;
    yt[(size_t)b * HH + h] = og * tanhf(c);
}

// p_t = len * sigmoid( sum_i tanh(t1[b][i]) * v[i] ); window bounds.
// grid = B, block = 256. part2[ks][i][b]
__global__ __launch_bounds__(256) void pos_kernel(
    const float* __restrict__ part2, const float* __restrict__ v,
    const int* __restrict__ elen,
    float* __restrict__ p_out, int* __restrict__ lr_out)
{
    const int b = blockIdx.x;
    const int t = threadIdx.x;
    float acc = 0.0f;
    for (int i = t; i < HH; i += 256) {
        float s = 0.0f;
#pragma unroll
        for (int ks = 0; ks < KS2; ++ks)
            s += part2[((size_t)ks * HH + i) * BB + b];
        acc += tanhf(s) * v[i];
    }
    __shared__ float red[256];
    red[t] = acc;
    __syncthreads();
    if (t < 128) red[t] += red[t + 128];
    __syncthreads();
    if (t < 64) {
        float x = red[t] + red[t + 64];
#pragma unroll
        for (int off = 32; off; off >>= 1) x += __shfl_xor(x, off);
        if (t == 0) {
            const float pt  = sigmoidf_(x);
            const float len = (float)elen[b];
            const float p   = len * pt;
            const int   pf  = (int)floorf(p);
            const int   left  = max(0, pf - DD);
            const int   right = min(elen[b], pf + DD);
            p_out[b] = p;
            lr_out[b * 2 + 0] = left;
            lr_out[b * 2 + 1] = right;
        }
    }
}

// Windowed raw scores. grid = (B, 16), block = 256 (4 waves, 2 si each).
// Writes sc[b][0..128) with -1e30 padding beyond window.
__global__ __launch_bounds__(256) void attn_scores(
    const float* __restrict__ encode_h, const float* __restrict__ yt,
    const int* __restrict__ lr, float* __restrict__ sc_out)
{
    const int b = blockIdx.x;
    const int q = blockIdx.y;
    const int t = threadIdx.x;
    const int lane = t & 63;
    const int wv = t >> 6;

    __shared__ float yts[HH];
    *(float4*)&yts[t * 4] = *(const float4*)&yt[(size_t)b * HH + t * 4];
    const int left = lr[b * 2], right = lr[b * 2 + 1];
    const int wsize = right - left;
    __syncthreads();

#pragma unroll
    for (int rr = 0; rr < 2; ++rr) {
        const int si = q * 8 + wv * 2 + rr;
        float s = -1e30f;
        if (si < wsize) {
            const float* eh = encode_h + ((size_t)b * SS + (left + si)) * HH;
            s = 0.0f;
#pragma unroll
            for (int cc = 0; cc < 4; ++cc) {
                const int hb = cc * 256 + lane * 4;
                float4 e = *(const float4*)(eh + hb);
                s += e.x * yts[hb] + e.y * yts[hb + 1] + e.z * yts[hb + 2] + e.w * yts[hb + 3];
            }
#pragma unroll
            for (int off = 32; off; off >>= 1) s += __shfl_xor(s, off);
        }
        if (lane == 0) sc_out[b * 2 * DD + si] = s;
    }
}

// Fused softmax+gauss+ct: grid = (B, 4), block = 512; half-split over si.
__global__ __launch_bounds__(512) void attn_ct(
    const float* __restrict__ encode_h, const float* __restrict__ sc,
    const float* __restrict__ p_buf, const int* __restrict__ lr,
    float* __restrict__ ct)
{
    const int b = blockIdx.x;
    const int t = threadIdx.x;
    const int lane = t & 63;
    const int hh = t & 255;
    const int half = t >> 8;
    const int h = blockIdx.y * 256 + hh;

    __shared__ float scs[2 * DD];
    __shared__ float ats[2 * DD];
    __shared__ float red[256];

    const int left = lr[b * 2];
    if (t < 2 * DD) scs[t] = sc[b * 2 * DD + t];
    __syncthreads();

    float m = fmaxf(scs[lane], scs[lane + 64]);
#pragma unroll
    for (int off = 32; off; off >>= 1) m = fmaxf(m, __shfl_xor(m, off));
    float ssum = expf(scs[lane] - m) + expf(scs[lane + 64] - m);
#pragma unroll
    for (int off = 32; off; off >>= 1) ssum += __shfl_xor(ssum, off);
    const float inv = 1.0f / ssum;

    if (t < 2 * DD) {
        const float dj = (float)(left + t) - p_buf[b];
        ats[t] = expf(scs[t] - m) * inv * expf(-(dj * dj) * (1.0f / 2048.0f));
    }
    __syncthreads();

    const float* ehb = encode_h + ((size_t)b * SS + left + half * 64) * HH + h;
    const float* atp = &ats[half * 64];
    float a0 = 0, a1 = 0, a2 = 0, a3 = 0, a4 = 0, a5 = 0, a6 = 0, a7 = 0;
#pragma unroll 2
    for (int si = 0; si < 64; si += 8) {
        a0 = fmaf(atp[si + 0], ehb[(size_t)(si + 0) * HH], a0);
        a1 = fmaf(atp[si + 1], ehb[(size_t)(si + 1) * HH], a1);
        a2 = fmaf(atp[si + 2], ehb[(size_t)(si + 2) * HH], a2);
        a3 = fmaf(atp[si + 3], ehb[(size_t)(si + 3) * HH], a3);
        a4 = fmaf(atp[si + 4], ehb[(size_t)(si + 4) * HH], a4);
        a5 = fmaf(atp[si + 5], ehb[(size_t)(si + 5) * HH], a5);
        a6 = fmaf(atp[si + 6], ehb[(size_t)(si + 6) * HH], a6);
        a7 = fmaf(atp[si + 7], ehb[(size_t)(si + 7) * HH], a7);
    }
    const float a = ((a0 + a1) + (a2 + a3)) + ((a4 + a5) + (a6 + a7));

    if (half == 1) red[hh] = a;
    __syncthreads();
    if (half == 0) ct[(size_t)b * HH + h] = a + red[hh];
}

// out[b][j] = sum_ks part3[ks][j][b].  grid = H/4 = 256, block = 256 (coalesced reads).
__global__ __launch_bounds__(256) void reduce_out(
    const float* __restrict__ part3, float* __restrict__ out)
{
    const int t = threadIdx.x;
    const int b = t & 63;
    const int j = blockIdx.x * 4 + (t >> 6);
    float s = 0.0f;
#pragma unroll
    for (int ks = 0; ks < KS2; ++ks)
        s += part3[((size_t)ks * HH + j) * BB + b];
    out[(size_t)b * HH + j] = s;
}

extern "C" void kernel_launch(void* const* d_in, const int* in_sizes, int n_in,
                              void* d_out, int out_size, void* d_ws, size_t ws_size,
                              hipStream_t stream)
{
    const float* encode_h = (const float*)d_in[0];
    const float* x_t      = (const float*)d_in[1];
    const float* h0       = (const float*)d_in[2];
    const float* c0       = (const float*)d_in[3];
    const float* W_ih     = (const float*)d_in[4];
    const float* W_hh     = (const float*)d_in[5];
    const float* b_ih     = (const float*)d_in[6];
    const float* b_hh     = (const float*)d_in[7];
    const float* W_ht2tan = (const float*)d_in[8];
    const float* W_tan2pt = (const float*)d_in[9];
    const float* W_ct2ht  = (const float*)d_in[10];
    const int*   elen     = (const int*)d_in[11];
    float* out = (float*)d_out;

    float* ws = (float*)d_ws;
    float* gates_part = ws;                                   // KS1*4096*64 = 4M
    float* yt    = gates_part + (size_t)KS1 * G4H * BB;       // 65536
    float* part2 = yt + (size_t)BB * HH;                      // KS2*1024*64 = 1M
    float* pbuf  = part2 + (size_t)KS2 * HH * BB;             // 64
    int*   lrbuf = (int*)(pbuf + BB);                         // 128 ints
    float* scbuf = pbuf + BB + 2 * BB;                        // 64*128
    float* ctbuf = scbuf + (size_t)BB * 2 * DD;               // 65536
    float* part3 = ctbuf + (size_t)BB * HH;                   // KS2*1024*64 = 1M

    // K1: gates partial GEMM (K = 2048 | 1024 concat), grid (64,16) = 1024 blocks (4/CU)
    dim3 g1(G4H / 64, KS1);
    gemm_mfma<<<g1, 256, 0, stream>>>(x_t, EE + HH, h0, HH,
                                      W_ih, EE + HH, W_hh, HH,
                                      2048, 3072, G4H, gates_part);
    // K2: LSTM cell -> yt
    lstm_cell<<<HH / 4, 256, 0, stream>>>(gates_part, b_ih, b_hh, c0, yt);

    // K3a: t1 = yt @ W_ht2tan^T (partials), grid (16,16) = 256 blocks
    dim3 g3(HH / 64, KS2);
    gemm_mfma<<<g3, 256, 0, stream>>>(yt, HH, yt, HH,
                                      W_ht2tan, HH, W_ht2tan, HH,
                                      HH, HH, HH, part2);
    // K3b: p, window bounds
    pos_kernel<<<BB, 256, 0, stream>>>(part2, W_tan2pt, elen, pbuf, lrbuf);

    // K4a: windowed raw scores, grid (64,16) = 1024 blocks (2 si per wave)
    dim3 g4a(BB, 16);
    attn_scores<<<g4a, 256, 0, stream>>>(encode_h, yt, lrbuf, scbuf);
    // K4b: softmax + gauss + ct, grid (64,4), block 512
    dim3 g4b(BB, 4);
    attn_ct<<<g4b, 512, 0, stream>>>(encode_h, scbuf, pbuf, lrbuf, ctbuf);

    // K5: ht partials = ct @ W_ct2ht^T, grid (16,16)
    gemm_mfma<<<g3, 256, 0, stream>>>(ctbuf, HH, ctbuf, HH,
                                      W_ct2ht, HH, W_ct2ht, HH,
                                      HH, HH, HH, part3);
    // K6: reduce -> out
    reduce_out<<<HH / 4, 256, 0, stream>>>(part3, out);
}

// Round 11
// 60.492 us; speedup vs baseline: 7.9704x; 1.2298x over previous
//
#include <hip/hip_runtime.h>
#include <hip/hip_bf16.h>
#include <math.h>

// Problem constants
#define BB 64
#define SS 2048
#define HH 1024
#define EE 1024
#define DD 64          // window half-size
#define G4H 4096       // 4*H
#define KS1 16         // k-splits for gates GEMM (K=3072, kchunk=192) -> 1024 blocks, 4/CU
#define KS2 16         // k-splits for the H=1024 GEMMs (kchunk=64)

typedef __attribute__((ext_vector_type(8))) short short8;
typedef __attribute__((ext_vector_type(4))) float floatx4;

#define MFMA_BF16(a, b, c) __builtin_amdgcn_mfma_f32_16x16x32_bf16((a), (b), (c), 0, 0, 0)

__device__ __forceinline__ float sigmoidf_(float x) { return 1.0f / (1.0f + expf(-x)); }

__device__ __forceinline__ ushort f2bf(float f) {
    return __builtin_bit_cast(ushort, __float2bfloat16(f));
}
__device__ __forceinline__ float bf2f(ushort h) {
    return __uint_as_float(((uint)h) << 16);
}

// split float4 into hi/lo bf16 pairs and store to LDS tiles (row stride 72 ushorts = 144 B)
__device__ __forceinline__ void stage_split(ushort* hbase, ushort* lbase, int row, int col, float4 v) {
    const ushort hx = f2bf(v.x), hy = f2bf(v.y), hz = f2bf(v.z), hw = f2bf(v.w);
    const float  lx = v.x - bf2f(hx), ly = v.y - bf2f(hy);
    const float  lz = v.z - bf2f(hz), lw = v.w - bf2f(hw);
    uint2 hp, lp;
    hp.x = (uint)hx | ((uint)hy << 16);
    hp.y = (uint)hz | ((uint)hw << 16);
    lp.x = (uint)f2bf(lx) | ((uint)f2bf(ly) << 16);
    lp.y = (uint)f2bf(lz) | ((uint)f2bf(lw) << 16);
    *(uint2*)(hbase + row * 72 + col) = hp;
    *(uint2*)(lbase + row * 72 + col) = lp;
}

// bf16x3 split-MFMA partial GEMM: partial = sum_{k in chunk} Xrow(b,k)*Wrow(j,k)
// X/W are each a concat of two row-major matrices along k (split at k1len).
// Tile: 64 j x 64 b x 64 k. 4 waves; wave w owns j-subtile w. grid=(Jtot/64, KS), block=256.
// STORE_BJ=false: part[ks][j][b] (scalar stores). STORE_BJ=true: part[ks][b][j] (float4 stores).
template<bool STORE_BJ>
__global__ __launch_bounds__(256) void gemm_mfma(
    const float* __restrict__ X1, int x1ld,
    const float* __restrict__ X2, int x2ld,
    const float* __restrict__ W1, int w1ld,
    const float* __restrict__ W2, int w2ld,
    int k1len, int Ktot, int Jtot,
    float* __restrict__ part)
{
    const int jt = blockIdx.x;
    const int ks = blockIdx.y;
    const int KS = gridDim.y;
    const int kchunk = Ktot / KS;
    const int k0 = ks * kchunk;
    const int t  = threadIdx.x;

    const int c = t & 15;
    const int r = t >> 4;
    const int lane = t & 63;
    const int wj   = t >> 6;
    const int rr   = lane & 15;
    const int kg   = lane >> 4;

    __shared__ __align__(16) ushort Wh[64][72];
    __shared__ __align__(16) ushort Wl[64][72];
    __shared__ __align__(16) ushort Xh[64][72];
    __shared__ __align__(16) ushort Xl[64][72];

    floatx4 acc[4];
#pragma unroll
    for (int bs = 0; bs < 4; ++bs) acc[bs] = (floatx4){0.f, 0.f, 0.f, 0.f};

    for (int kk = k0; kk < k0 + kchunk; kk += 64) {
        const int kg4 = kk + 4 * c;
#pragma unroll
        for (int i = 0; i < 4; ++i) {
            const int row = r + 16 * i;
            const float* xs = (kg4 < k1len) ? (X1 + (size_t)row * x1ld + kg4)
                                            : (X2 + (size_t)row * x2ld + (kg4 - k1len));
            float4 xv = *(const float4*)xs;
            const int j = jt * 64 + row;
            const float* wsrc = (kg4 < k1len) ? (W1 + (size_t)j * w1ld + kg4)
                                              : (W2 + (size_t)j * w2ld + (kg4 - k1len));
            float4 wv = *(const float4*)wsrc;
            stage_split(&Xh[0][0], &Xl[0][0], row, 4 * c, xv);
            stage_split(&Wh[0][0], &Wl[0][0], row, 4 * c, wv);
        }
        __syncthreads();

        const int aoff = (wj * 16 + rr) * 72 + kg * 8;
        short8 ah[2], al[2];
        ah[0] = *(const short8*)((const void*)(&Wh[0][0] + aoff));
        ah[1] = *(const short8*)((const void*)(&Wh[0][0] + aoff + 32));
        al[0] = *(const short8*)((const void*)(&Wl[0][0] + aoff));
        al[1] = *(const short8*)((const void*)(&Wl[0][0] + aoff + 32));

#pragma unroll
        for (int bs = 0; bs < 4; ++bs) {
            const int boff = (bs * 16 + rr) * 72 + kg * 8;
#pragma unroll
            for (int kh = 0; kh < 2; ++kh) {
                short8 bh = *(const short8*)((const void*)(&Xh[0][0] + boff + kh * 32));
                short8 bl = *(const short8*)((const void*)(&Xl[0][0] + boff + kh * 32));
                acc[bs] = MFMA_BF16(ah[kh], bh, acc[bs]);   // hi*hi
                acc[bs] = MFMA_BF16(al[kh], bh, acc[bs]);   // lo*hi
                acc[bs] = MFMA_BF16(ah[kh], bl, acc[bs]);   // hi*lo
            }
        }
        __syncthreads();
    }

    // C/D layout: col = lane&15 (b within subtile), row = (lane>>4)*4 + reg (j within subtile)
    if (STORE_BJ) {
        // part[ks][b][j]: reg is consecutive j -> one float4 store per bs
        const int j0 = jt * 64 + wj * 16 + kg * 4;
#pragma unroll
        for (int bs = 0; bs < 4; ++bs) {
            const int b = bs * 16 + rr;
            *(float4*)&part[((size_t)ks * BB + b) * Jtot + j0] =
                (float4){acc[bs][0], acc[bs][1], acc[bs][2], acc[bs][3]};
        }
    } else {
#pragma unroll
        for (int bs = 0; bs < 4; ++bs) {
#pragma unroll
            for (int reg = 0; reg < 4; ++reg) {
                const int j = jt * 64 + wj * 16 + kg * 4 + reg;
                const int b = bs * 16 + rr;
                part[((size_t)ks * Jtot + j) * BB + b] = acc[bs][reg];
            }
        }
    }
}

// LSTM cell from gate partials (layout [ks][j][b]). grid = H/4 = 256 blocks, block = 256.
__global__ __launch_bounds__(256) void lstm_cell(
    const float* __restrict__ part,
    const float* __restrict__ b_ih, const float* __restrict__ b_hh,
    const float* __restrict__ c0, float* __restrict__ yt)
{
    const int t = threadIdx.x;
    const int b = t & 63;
    const int h = blockIdx.x * 4 + (t >> 6);

    float g4[4];
#pragma unroll
    for (int q = 0; q < 4; ++q) {
        const int j = h + q * HH;
        float s = b_ih[j] + b_hh[j];
#pragma unroll
        for (int ks = 0; ks < KS1; ++ks)
            s += part[((size_t)ks * G4H + j) * BB + b];
        g4[q] = s;
    }
    const float ig = sigmoidf_(g4[0]);
    const float fg = sigmoidf_(g4[1]);
    const float gg = tanhf(g4[2]);
    const float og = sigmoidf_(g4[3]);
    const float c  = fg * c0[(size_t)b * HH + h] + ig * gg;
    yt[(size_t)b * HH + h] = og * tanhf(c);
}

// p_t = len * sigmoid( sum_i tanh(t1[b][i]) * v[i] ); window bounds.
// part2 layout [ks][b][i] -> coalesced float4 reads. grid = B, block = 256.
__global__ __launch_bounds__(256) void pos_kernel(
    const float* __restrict__ part2, const float* __restrict__ v,
    const int* __restrict__ elen,
    float* __restrict__ p_out, int* __restrict__ lr_out)
{
    const int b = blockIdx.x;
    const int t = threadIdx.x;

    float4 s = {0.f, 0.f, 0.f, 0.f};
#pragma unroll
    for (int ks = 0; ks < KS2; ++ks) {
        float4 pv = *(const float4*)&part2[((size_t)ks * BB + b) * HH + t * 4];
        s.x += pv.x; s.y += pv.y; s.z += pv.z; s.w += pv.w;
    }
    const float4 vv = *(const float4*)&v[t * 4];
    float acc = tanhf(s.x) * vv.x + tanhf(s.y) * vv.y
              + tanhf(s.z) * vv.z + tanhf(s.w) * vv.w;

    __shared__ float red[256];
    red[t] = acc;
    __syncthreads();
    if (t < 128) red[t] += red[t + 128];
    __syncthreads();
    if (t < 64) {
        float x = red[t] + red[t + 64];
#pragma unroll
        for (int off = 32; off; off >>= 1) x += __shfl_xor(x, off);
        if (t == 0) {
            const float pt  = sigmoidf_(x);
            const float len = (float)elen[b];
            const float p   = len * pt;
            const int   pf  = (int)floorf(p);
            const int   left  = max(0, pf - DD);
            const int   right = min(elen[b], pf + DD);
            p_out[b] = p;
            lr_out[b * 2 + 0] = left;
            lr_out[b * 2 + 1] = right;
        }
    }
}

// Windowed raw scores. grid = (B, 16), block = 256 (4 waves, 2 si each).
// Writes sc[b][0..128) with -1e30 padding beyond window.
__global__ __launch_bounds__(256) void attn_scores(
    const float* __restrict__ encode_h, const float* __restrict__ yt,
    const int* __restrict__ lr, float* __restrict__ sc_out)
{
    const int b = blockIdx.x;
    const int q = blockIdx.y;
    const int t = threadIdx.x;
    const int lane = t & 63;
    const int wv = t >> 6;

    __shared__ float yts[HH];
    *(float4*)&yts[t * 4] = *(const float4*)&yt[(size_t)b * HH + t * 4];
    const int left = lr[b * 2], right = lr[b * 2 + 1];
    const int wsize = right - left;
    __syncthreads();

#pragma unroll
    for (int rr = 0; rr < 2; ++rr) {
        const int si = q * 8 + wv * 2 + rr;
        float s = -1e30f;
        if (si < wsize) {
            const float* eh = encode_h + ((size_t)b * SS + (left + si)) * HH;
            s = 0.0f;
#pragma unroll
            for (int cc = 0; cc < 4; ++cc) {
                const int hb = cc * 256 + lane * 4;
                float4 e = *(const float4*)(eh + hb);
                s += e.x * yts[hb] + e.y * yts[hb + 1] + e.z * yts[hb + 2] + e.w * yts[hb + 3];
            }
#pragma unroll
            for (int off = 32; off; off >>= 1) s += __shfl_xor(s, off);
        }
        if (lane == 0) sc_out[b * 2 * DD + si] = s;
    }
}

// Fused softmax+gauss+ct: grid = (B, 4), block = 512; half-split over si.
__global__ __launch_bounds__(512) void attn_ct(
    const float* __restrict__ encode_h, const float* __restrict__ sc,
    const float* __restrict__ p_buf, const int* __restrict__ lr,
    float* __restrict__ ct)
{
    const int b = blockIdx.x;
    const int t = threadIdx.x;
    const int lane = t & 63;
    const int hh = t & 255;
    const int half = t >> 8;
    const int h = blockIdx.y * 256 + hh;

    __shared__ float scs[2 * DD];
    __shared__ float ats[2 * DD];
    __shared__ float red[256];

    const int left = lr[b * 2];
    if (t < 2 * DD) scs[t] = sc[b * 2 * DD + t];
    __syncthreads();

    float m = fmaxf(scs[lane], scs[lane + 64]);
#pragma unroll
    for (int off = 32; off; off >>= 1) m = fmaxf(m, __shfl_xor(m, off));
    float ssum = expf(scs[lane] - m) + expf(scs[lane + 64] - m);
#pragma unroll
    for (int off = 32; off; off >>= 1) ssum += __shfl_xor(ssum, off);
    const float inv = 1.0f / ssum;

    if (t < 2 * DD) {
        const float dj = (float)(left + t) - p_buf[b];
        ats[t] = expf(scs[t] - m) * inv * expf(-(dj * dj) * (1.0f / 2048.0f));
    }
    __syncthreads();

    const float* ehb = encode_h + ((size_t)b * SS + left + half * 64) * HH + h;
    const float* atp = &ats[half * 64];
    float a0 = 0, a1 = 0, a2 = 0, a3 = 0, a4 = 0, a5 = 0, a6 = 0, a7 = 0;
#pragma unroll 2
    for (int si = 0; si < 64; si += 8) {
        a0 = fmaf(atp[si + 0], ehb[(size_t)(si + 0) * HH], a0);
        a1 = fmaf(atp[si + 1], ehb[(size_t)(si + 1) * HH], a1);
        a2 = fmaf(atp[si + 2], ehb[(size_t)(si + 2) * HH], a2);
        a3 = fmaf(atp[si + 3], ehb[(size_t)(si + 3) * HH], a3);
        a4 = fmaf(atp[si + 4], ehb[(size_t)(si + 4) * HH], a4);
        a5 = fmaf(atp[si + 5], ehb[(size_t)(si + 5) * HH], a5);
        a6 = fmaf(atp[si + 6], ehb[(size_t)(si + 6) * HH], a6);
        a7 = fmaf(atp[si + 7], ehb[(size_t)(si + 7) * HH], a7);
    }
    const float a = ((a0 + a1) + (a2 + a3)) + ((a4 + a5) + (a6 + a7));

    if (half == 1) red[hh] = a;
    __syncthreads();
    if (half == 0) ct[(size_t)b * HH + h] = a + red[hh];
}

// out[b][j] = sum_ks part3[ks][j][b].  grid = H/4 = 256, block = 256 (coalesced reads).
__global__ __launch_bounds__(256) void reduce_out(
    const float* __restrict__ part3, float* __restrict__ out)
{
    const int t = threadIdx.x;
    const int b = t & 63;
    const int j = blockIdx.x * 4 + (t >> 6);
    float s = 0.0f;
#pragma unroll
    for (int ks = 0; ks < KS2; ++ks)
        s += part3[((size_t)ks * HH + j) * BB + b];
    out[(size_t)b * HH + j] = s;
}

extern "C" void kernel_launch(void* const* d_in, const int* in_sizes, int n_in,
                              void* d_out, int out_size, void* d_ws, size_t ws_size,
                              hipStream_t stream)
{
    const float* encode_h = (const float*)d_in[0];
    const float* x_t      = (const float*)d_in[1];
    const float* h0       = (const float*)d_in[2];
    const float* c0       = (const float*)d_in[3];
    const float* W_ih     = (const float*)d_in[4];
    const float* W_hh     = (const float*)d_in[5];
    const float* b_ih     = (const float*)d_in[6];
    const float* b_hh     = (const float*)d_in[7];
    const float* W_ht2tan = (const float*)d_in[8];
    const float* W_tan2pt = (const float*)d_in[9];
    const float* W_ct2ht  = (const float*)d_in[10];
    const int*   elen     = (const int*)d_in[11];
    float* out = (float*)d_out;

    float* ws = (float*)d_ws;
    float* gates_part = ws;                                   // KS1*4096*64 = 4M
    float* yt    = gates_part + (size_t)KS1 * G4H * BB;       // 65536
    float* part2 = yt + (size_t)BB * HH;                      // KS2*1024*64 = 1M
    float* pbuf  = part2 + (size_t)KS2 * HH * BB;             // 64
    int*   lrbuf = (int*)(pbuf + BB);                         // 128 ints
    float* scbuf = pbuf + BB + 2 * BB;                        // 64*128
    float* ctbuf = scbuf + (size_t)BB * 2 * DD;               // 65536
    float* part3 = ctbuf + (size_t)BB * HH;                   // KS2*1024*64 = 1M

    // K1: gates partial GEMM (K = 2048 | 1024 concat), grid (64,16) = 1024 blocks (4/CU)
    dim3 g1(G4H / 64, KS1);
    gemm_mfma<false><<<g1, 256, 0, stream>>>(x_t, EE + HH, h0, HH,
                                             W_ih, EE + HH, W_hh, HH,
                                             2048, 3072, G4H, gates_part);
    // K2: LSTM cell -> yt
    lstm_cell<<<HH / 4, 256, 0, stream>>>(gates_part, b_ih, b_hh, c0, yt);

    // K3a: t1 = yt @ W_ht2tan^T (partials, [ks][b][j] layout), grid (16,16) = 256 blocks
    dim3 g3(HH / 64, KS2);
    gemm_mfma<true><<<g3, 256, 0, stream>>>(yt, HH, yt, HH,
                                            W_ht2tan, HH, W_ht2tan, HH,
                                            HH, HH, HH, part2);
    // K3b: p, window bounds (coalesced float4 reads of part2)
    pos_kernel<<<BB, 256, 0, stream>>>(part2, W_tan2pt, elen, pbuf, lrbuf);

    // K4a: windowed raw scores, grid (64,16) = 1024 blocks (2 si per wave)
    dim3 g4a(BB, 16);
    attn_scores<<<g4a, 256, 0, stream>>>(encode_h, yt, lrbuf, scbuf);
    // K4b: softmax + gauss + ct, grid (64,4), block 512
    dim3 g4b(BB, 4);
    attn_ct<<<g4b, 512, 0, stream>>>(encode_h, scbuf, pbuf, lrbuf, ctbuf);

    // K5: ht partials = ct @ W_ct2ht^T, grid (16,16), [ks][j][b] layout
    gemm_mfma<false><<<g3, 256, 0, stream>>>(ctbuf, HH, ctbuf, HH,
                                             W_ct2ht, HH, W_ct2ht, HH,
                                             HH, HH, HH, part3);
    // K6: reduce -> out
    reduce_out<<<HH / 4, 256, 0, stream>>>(part3, out);
}

// Round 12
// 59.996 us; speedup vs baseline: 8.0363x; 1.0083x over previous
//
#include <hip/hip_runtime.h>
#include <hip/hip_bf16.h>
#include <math.h>

// Problem constants
#define BB 64
#define SS 2048
#define HH 1024
#define EE 1024
#define DD 64          // window half-size
#define G4H 4096       // 4*H
#define KS1 16         // k-splits for gates GEMM (K=3072, kchunk=192) -> 1024 blocks, 4/CU
#define KS2 16         // k-splits for the H=1024 GEMMs (kchunk=64)

typedef __attribute__((ext_vector_type(8))) short short8;
typedef __attribute__((ext_vector_type(4))) float floatx4;

#define MFMA_BF16(a, b, c) __builtin_amdgcn_mfma_f32_16x16x32_bf16((a), (b), (c), 0, 0, 0)

__device__ __forceinline__ float sigmoidf_(float x) { return 1.0f / (1.0f + expf(-x)); }

__device__ __forceinline__ ushort f2bf(float f) {
    return __builtin_bit_cast(ushort, __float2bfloat16(f));
}
__device__ __forceinline__ float bf2f(ushort h) {
    return __uint_as_float(((uint)h) << 16);
}

// split float4 into hi/lo bf16 pairs and store to LDS tiles (row stride 72 ushorts = 144 B)
__device__ __forceinline__ void stage_split(ushort* hbase, ushort* lbase, int row, int col, float4 v) {
    const ushort hx = f2bf(v.x), hy = f2bf(v.y), hz = f2bf(v.z), hw = f2bf(v.w);
    const float  lx = v.x - bf2f(hx), ly = v.y - bf2f(hy);
    const float  lz = v.z - bf2f(hz), lw = v.w - bf2f(hw);
    uint2 hp, lp;
    hp.x = (uint)hx | ((uint)hy << 16);
    hp.y = (uint)hz | ((uint)hw << 16);
    lp.x = (uint)f2bf(lx) | ((uint)f2bf(ly) << 16);
    lp.y = (uint)f2bf(lz) | ((uint)f2bf(lw) << 16);
    *(uint2*)(hbase + row * 72 + col) = hp;
    *(uint2*)(lbase + row * 72 + col) = lp;
}

// bf16x3 split-MFMA partial GEMM: partial = sum_{k in chunk} Xrow(b,k)*Wrow(j,k)
// X/W are each a concat of two row-major matrices along k (split at k1len).
// Tile: 64 j x 64 b x 64 k. 4 waves; wave w owns j-subtile w. grid=(Jtot/64, KS), block=256.
// STORE_BJ=false: part[ks][j][b] (scalar stores). STORE_BJ=true: part[ks][b][j] (float4 stores).
template<bool STORE_BJ>
__global__ __launch_bounds__(256) void gemm_mfma(
    const float* __restrict__ X1, int x1ld,
    const float* __restrict__ X2, int x2ld,
    const float* __restrict__ W1, int w1ld,
    const float* __restrict__ W2, int w2ld,
    int k1len, int Ktot, int Jtot,
    float* __restrict__ part)
{
    const int jt = blockIdx.x;
    const int ks = blockIdx.y;
    const int KS = gridDim.y;
    const int kchunk = Ktot / KS;
    const int k0 = ks * kchunk;
    const int t  = threadIdx.x;

    const int c = t & 15;
    const int r = t >> 4;
    const int lane = t & 63;
    const int wj   = t >> 6;
    const int rr   = lane & 15;
    const int kg   = lane >> 4;

    __shared__ __align__(16) ushort Wh[64][72];
    __shared__ __align__(16) ushort Wl[64][72];
    __shared__ __align__(16) ushort Xh[64][72];
    __shared__ __align__(16) ushort Xl[64][72];

    floatx4 acc[4];
#pragma unroll
    for (int bs = 0; bs < 4; ++bs) acc[bs] = (floatx4){0.f, 0.f, 0.f, 0.f};

    for (int kk = k0; kk < k0 + kchunk; kk += 64) {
        const int kg4 = kk + 4 * c;
#pragma unroll
        for (int i = 0; i < 4; ++i) {
            const int row = r + 16 * i;
            const float* xs = (kg4 < k1len) ? (X1 + (size_t)row * x1ld + kg4)
                                            : (X2 + (size_t)row * x2ld + (kg4 - k1len));
            float4 xv = *(const float4*)xs;
            const int j = jt * 64 + row;
            const float* wsrc = (kg4 < k1len) ? (W1 + (size_t)j * w1ld + kg4)
                                              : (W2 + (size_t)j * w2ld + (kg4 - k1len));
            float4 wv = *(const float4*)wsrc;
            stage_split(&Xh[0][0], &Xl[0][0], row, 4 * c, xv);
            stage_split(&Wh[0][0], &Wl[0][0], row, 4 * c, wv);
        }
        __syncthreads();

        const int aoff = (wj * 16 + rr) * 72 + kg * 8;
        short8 ah[2], al[2];
        ah[0] = *(const short8*)((const void*)(&Wh[0][0] + aoff));
        ah[1] = *(const short8*)((const void*)(&Wh[0][0] + aoff + 32));
        al[0] = *(const short8*)((const void*)(&Wl[0][0] + aoff));
        al[1] = *(const short8*)((const void*)(&Wl[0][0] + aoff + 32));

#pragma unroll
        for (int bs = 0; bs < 4; ++bs) {
            const int boff = (bs * 16 + rr) * 72 + kg * 8;
#pragma unroll
            for (int kh = 0; kh < 2; ++kh) {
                short8 bh = *(const short8*)((const void*)(&Xh[0][0] + boff + kh * 32));
                short8 bl = *(const short8*)((const void*)(&Xl[0][0] + boff + kh * 32));
                acc[bs] = MFMA_BF16(ah[kh], bh, acc[bs]);   // hi*hi
                acc[bs] = MFMA_BF16(al[kh], bh, acc[bs]);   // lo*hi
                acc[bs] = MFMA_BF16(ah[kh], bl, acc[bs]);   // hi*lo
            }
        }
        __syncthreads();
    }

    // C/D layout: col = lane&15 (b within subtile), row = (lane>>4)*4 + reg (j within subtile)
    if (STORE_BJ) {
        // part[ks][b][j]: reg is consecutive j -> one float4 store per bs
        const int j0 = jt * 64 + wj * 16 + kg * 4;
#pragma unroll
        for (int bs = 0; bs < 4; ++bs) {
            const int b = bs * 16 + rr;
            *(float4*)&part[((size_t)ks * BB + b) * Jtot + j0] =
                (float4){acc[bs][0], acc[bs][1], acc[bs][2], acc[bs][3]};
        }
    } else {
#pragma unroll
        for (int bs = 0; bs < 4; ++bs) {
#pragma unroll
            for (int reg = 0; reg < 4; ++reg) {
                const int j = jt * 64 + wj * 16 + kg * 4 + reg;
                const int b = bs * 16 + rr;
                part[((size_t)ks * Jtot + j) * BB + b] = acc[bs][reg];
            }
        }
    }
}

// LSTM cell from gate partials (layout [ks][j][b]). grid = H/4 = 256 blocks, block = 256.
__global__ __launch_bounds__(256) void lstm_cell(
    const float* __restrict__ part,
    const float* __restrict__ b_ih, const float* __restrict__ b_hh,
    const float* __restrict__ c0, float* __restrict__ yt)
{
    const int t = threadIdx.x;
    const int b = t & 63;
    const int h = blockIdx.x * 4 + (t >> 6);

    float g4[4];
#pragma unroll
    for (int q = 0; q < 4; ++q) {
        const int j = h + q * HH;
        float s = b_ih[j] + b_hh[j];
#pragma unroll
        for (int ks = 0; ks < KS1; ++ks)
            s += part[((size_t)ks * G4H + j) * BB + b];
        g4[q] = s;
    }
    const float ig = sigmoidf_(g4[0]);
    const float fg = sigmoidf_(g4[1]);
    const float gg = tanhf(g4[2]);
    const float og = sigmoidf_(g4[3]);
    const float c  = fg * c0[(size_t)b * HH + h] + ig * gg;
    yt[(size_t)b * HH + h] = og * tanhf(c);
}

// p_t = len * sigmoid( sum_i tanh(t1[b][i]) * v[i] ); window bounds.
// part2 layout [ks][b][i] -> coalesced float4 reads. grid = B, block = 256.
__global__ __launch_bounds__(256) void pos_kernel(
    const float* __restrict__ part2, const float* __restrict__ v,
    const int* __restrict__ elen,
    float* __restrict__ p_out, int* __restrict__ lr_out)
{
    const int b = blockIdx.x;
    const int t = threadIdx.x;

    float4 s = {0.f, 0.f, 0.f, 0.f};
#pragma unroll
    for (int ks = 0; ks < KS2; ++ks) {
        float4 pv = *(const float4*)&part2[((size_t)ks * BB + b) * HH + t * 4];
        s.x += pv.x; s.y += pv.y; s.z += pv.z; s.w += pv.w;
    }
    const float4 vv = *(const float4*)&v[t * 4];
    float acc = tanhf(s.x) * vv.x + tanhf(s.y) * vv.y
              + tanhf(s.z) * vv.z + tanhf(s.w) * vv.w;

    __shared__ float red[256];
    red[t] = acc;
    __syncthreads();
    if (t < 128) red[t] += red[t + 128];
    __syncthreads();
    if (t < 64) {
        float x = red[t] + red[t + 64];
#pragma unroll
        for (int off = 32; off; off >>= 1) x += __shfl_xor(x, off);
        if (t == 0) {
            const float pt  = sigmoidf_(x);
            const float len = (float)elen[b];
            const float p   = len * pt;
            const int   pf  = (int)floorf(p);
            const int   left  = max(0, pf - DD);
            const int   right = min(elen[b], pf + DD);
            p_out[b] = p;
            lr_out[b * 2 + 0] = left;
            lr_out[b * 2 + 1] = right;
        }
    }
}

// Windowed raw scores. grid = (B, 16), block = 256 (4 waves, 2 si each).
// Writes sc[b][0..128) with -1e30 padding beyond window.
__global__ __launch_bounds__(256) void attn_scores(
    const float* __restrict__ encode_h, const float* __restrict__ yt,
    const int* __restrict__ lr, float* __restrict__ sc_out)
{
    const int b = blockIdx.x;
    const int q = blockIdx.y;
    const int t = threadIdx.x;
    const int lane = t & 63;
    const int wv = t >> 6;

    __shared__ float yts[HH];
    *(float4*)&yts[t * 4] = *(const float4*)&yt[(size_t)b * HH + t * 4];
    const int left = lr[b * 2], right = lr[b * 2 + 1];
    const int wsize = right - left;
    __syncthreads();

#pragma unroll
    for (int rr = 0; rr < 2; ++rr) {
        const int si = q * 8 + wv * 2 + rr;
        float s = -1e30f;
        if (si < wsize) {
            const float* eh = encode_h + ((size_t)b * SS + (left + si)) * HH;
            s = 0.0f;
#pragma unroll
            for (int cc = 0; cc < 4; ++cc) {
                const int hb = cc * 256 + lane * 4;
                float4 e = *(const float4*)(eh + hb);
                s += e.x * yts[hb] + e.y * yts[hb + 1] + e.z * yts[hb + 2] + e.w * yts[hb + 3];
            }
#pragma unroll
            for (int off = 32; off; off >>= 1) s += __shfl_xor(s, off);
        }
        if (lane == 0) sc_out[b * 2 * DD + si] = s;
    }
}

// Fused softmax+gauss+ct: grid = (B, 8), block = 512 = 4 si-quarters x 128 h.
// Each quarter accumulates 32 si; 4-way LDS combine per h.
__global__ __launch_bounds__(512) void attn_ct(
    const float* __restrict__ encode_h, const float* __restrict__ sc,
    const float* __restrict__ p_buf, const int* __restrict__ lr,
    float* __restrict__ ct)
{
    const int b = blockIdx.x;
    const int t = threadIdx.x;
    const int lane = t & 63;
    const int hh = t & 127;          // h within 128-chunk
    const int q  = t >> 7;           // si-quarter 0..3
    const int h = blockIdx.y * 128 + hh;

    __shared__ float scs[2 * DD];
    __shared__ float ats[2 * DD];
    __shared__ float red[4][128];

    const int left = lr[b * 2];
    if (t < 2 * DD) scs[t] = sc[b * 2 * DD + t];
    __syncthreads();

    // per-wave redundant softmax stats over the 128 scores
    float m = fmaxf(scs[lane], scs[lane + 64]);
#pragma unroll
    for (int off = 32; off; off >>= 1) m = fmaxf(m, __shfl_xor(m, off));
    float ssum = expf(scs[lane] - m) + expf(scs[lane + 64] - m);
#pragma unroll
    for (int off = 32; off; off >>= 1) ssum += __shfl_xor(ssum, off);
    const float inv = 1.0f / ssum;

    if (t < 2 * DD) {
        const float dj = (float)(left + t) - p_buf[b];
        ats[t] = expf(scs[t] - m) * inv * expf(-(dj * dj) * (1.0f / 2048.0f));
    }
    __syncthreads();

    const float* ehb = encode_h + ((size_t)b * SS + left + q * 32) * HH + h;
    const float* atp = &ats[q * 32];
    float a0 = 0, a1 = 0, a2 = 0, a3 = 0, a4 = 0, a5 = 0, a6 = 0, a7 = 0;
#pragma unroll
    for (int si = 0; si < 32; si += 8) {
        a0 = fmaf(atp[si + 0], ehb[(size_t)(si + 0) * HH], a0);
        a1 = fmaf(atp[si + 1], ehb[(size_t)(si + 1) * HH], a1);
        a2 = fmaf(atp[si + 2], ehb[(size_t)(si + 2) * HH], a2);
        a3 = fmaf(atp[si + 3], ehb[(size_t)(si + 3) * HH], a3);
        a4 = fmaf(atp[si + 4], ehb[(size_t)(si + 4) * HH], a4);
        a5 = fmaf(atp[si + 5], ehb[(size_t)(si + 5) * HH], a5);
        a6 = fmaf(atp[si + 6], ehb[(size_t)(si + 6) * HH], a6);
        a7 = fmaf(atp[si + 7], ehb[(size_t)(si + 7) * HH], a7);
    }
    const float a = ((a0 + a1) + (a2 + a3)) + ((a4 + a5) + (a6 + a7));

    if (q != 0) red[q][hh] = a;
    __syncthreads();
    if (q == 0)
        ct[(size_t)b * HH + h] = (a + red[1][hh]) + (red[2][hh] + red[3][hh]);
}

// out[b][j] = sum_ks part3[ks][j][b].  grid = H/4 = 256, block = 256 (coalesced reads).
__global__ __launch_bounds__(256) void reduce_out(
    const float* __restrict__ part3, float* __restrict__ out)
{
    const int t = threadIdx.x;
    const int b = t & 63;
    const int j = blockIdx.x * 4 + (t >> 6);
    float s = 0.0f;
#pragma unroll
    for (int ks = 0; ks < KS2; ++ks)
        s += part3[((size_t)ks * HH + j) * BB + b];
    out[(size_t)b * HH + j] = s;
}

extern "C" void kernel_launch(void* const* d_in, const int* in_sizes, int n_in,
                              void* d_out, int out_size, void* d_ws, size_t ws_size,
                              hipStream_t stream)
{
    const float* encode_h = (const float*)d_in[0];
    const float* x_t      = (const float*)d_in[1];
    const float* h0       = (const float*)d_in[2];
    const float* c0       = (const float*)d_in[3];
    const float* W_ih     = (const float*)d_in[4];
    const float* W_hh     = (const float*)d_in[5];
    const float* b_ih     = (const float*)d_in[6];
    const float* b_hh     = (const float*)d_in[7];
    const float* W_ht2tan = (const float*)d_in[8];
    const float* W_tan2pt = (const float*)d_in[9];
    const float* W_ct2ht  = (const float*)d_in[10];
    const int*   elen     = (const int*)d_in[11];
    float* out = (float*)d_out;

    float* ws = (float*)d_ws;
    float* gates_part = ws;                                   // KS1*4096*64 = 4M
    float* yt    = gates_part + (size_t)KS1 * G4H * BB;       // 65536
    float* part2 = yt + (size_t)BB * HH;                      // KS2*1024*64 = 1M
    float* pbuf  = part2 + (size_t)KS2 * HH * BB;             // 64
    int*   lrbuf = (int*)(pbuf + BB);                         // 128 ints
    float* scbuf = pbuf + BB + 2 * BB;                        // 64*128
    float* ctbuf = scbuf + (size_t)BB * 2 * DD;               // 65536
    float* part3 = ctbuf + (size_t)BB * HH;                   // KS2*1024*64 = 1M

    // K1: gates partial GEMM (K = 2048 | 1024 concat), grid (64,16) = 1024 blocks (4/CU)
    dim3 g1(G4H / 64, KS1);
    gemm_mfma<false><<<g1, 256, 0, stream>>>(x_t, EE + HH, h0, HH,
                                             W_ih, EE + HH, W_hh, HH,
                                             2048, 3072, G4H, gates_part);
    // K2: LSTM cell -> yt
    lstm_cell<<<HH / 4, 256, 0, stream>>>(gates_part, b_ih, b_hh, c0, yt);

    // K3a: t1 = yt @ W_ht2tan^T (partials, [ks][b][j] layout), grid (16,16) = 256 blocks
    dim3 g3(HH / 64, KS2);
    gemm_mfma<true><<<g3, 256, 0, stream>>>(yt, HH, yt, HH,
                                            W_ht2tan, HH, W_ht2tan, HH,
                                            HH, HH, HH, part2);
    // K3b: p, window bounds (coalesced float4 reads of part2)
    pos_kernel<<<BB, 256, 0, stream>>>(part2, W_tan2pt, elen, pbuf, lrbuf);

    // K4a: windowed raw scores, grid (64,16) = 1024 blocks (2 si per wave)
    dim3 g4a(BB, 16);
    attn_scores<<<g4a, 256, 0, stream>>>(encode_h, yt, lrbuf, scbuf);
    // K4b: softmax + gauss + ct, grid (64,8) = 512 blocks, block 512 (4 si-quarters x 128 h)
    dim3 g4b(BB, 8);
    attn_ct<<<g4b, 512, 0, stream>>>(encode_h, scbuf, pbuf, lrbuf, ctbuf);

    // K5: ht partials = ct @ W_ct2ht^T, grid (16,16), [ks][j][b] layout
    gemm_mfma<false><<<g3, 256, 0, stream>>>(ctbuf, HH, ctbuf, HH,
                                             W_ct2ht, HH, W_ct2ht, HH,
                                             HH, HH, HH, part3);
    // K6: reduce -> out
    reduce_out<<<HH / 4, 256, 0, stream>>>(part3, out);
}

// Round 13
// 54.805 us; speedup vs baseline: 8.7976x; 1.0947x over previous
//
#include <hip/hip_runtime.h>
#include <hip/hip_bf16.h>
#include <math.h>

// Problem constants
#define BB 64
#define SS 2048
#define HH 1024
#define EE 1024
#define DD 64          // window half-size
#define G4H 4096       // 4*H
#define KS1 16         // k-splits for gates GEMM (K=3072, kchunk=192) -> 1024 blocks, 4/CU
#define KS2 16         // k-splits for the H=1024 GEMMs (kchunk=64)

typedef __attribute__((ext_vector_type(8))) short short8;
typedef __attribute__((ext_vector_type(4))) float floatx4;

#define MFMA_BF16(a, b, c) __builtin_amdgcn_mfma_f32_16x16x32_bf16((a), (b), (c), 0, 0, 0)

__device__ __forceinline__ float sigmoidf_(float x) { return 1.0f / (1.0f + expf(-x)); }

__device__ __forceinline__ ushort f2bf(float f) {
    return __builtin_bit_cast(ushort, __float2bfloat16(f));
}

// Truncation-based hi/lo bf16 split of a float4, stored to LDS (row stride 72 ushorts).
// hi = top 16 bits (trunc, bit-ops only); lo = (v - hi) rounded to bf16.
// Error: hi+lo representation ~2^-17 rel; missing lo*lo term in products ~2^-16 rel.
__device__ __forceinline__ void stage_split(ushort* hbase, ushort* lbase, int row, int col, float4 v) {
    const uint bx = __float_as_uint(v.x), by = __float_as_uint(v.y);
    const uint bz = __float_as_uint(v.z), bw = __float_as_uint(v.w);
    uint2 hp;
    hp.x = (bx >> 16) | (by & 0xffff0000u);
    hp.y = (bz >> 16) | (bw & 0xffff0000u);
    const float lx = v.x - __uint_as_float(bx & 0xffff0000u);
    const float ly = v.y - __uint_as_float(by & 0xffff0000u);
    const float lz = v.z - __uint_as_float(bz & 0xffff0000u);
    const float lw = v.w - __uint_as_float(bw & 0xffff0000u);
    uint2 lp;
    lp.x = (uint)f2bf(lx) | ((uint)f2bf(ly) << 16);
    lp.y = (uint)f2bf(lz) | ((uint)f2bf(lw) << 16);
    *(uint2*)(hbase + row * 72 + col) = hp;
    *(uint2*)(lbase + row * 72 + col) = lp;
}

// bf16x3 split-MFMA partial GEMM: partial = sum_{k in chunk} Xrow(b,k)*Wrow(j,k)
// X/W are each a concat of two row-major matrices along k (split at k1len).
// Tile: 64 j x 64 b x 64 k. 4 waves; wave w owns j-subtile w. grid=(Jtot/64, KS), block=256.
// STORE_BJ=false: part[ks][j][b] (scalar stores). STORE_BJ=true: part[ks][b][j] (float4 stores).
template<bool STORE_BJ>
__global__ __launch_bounds__(256) void gemm_mfma(
    const float* __restrict__ X1, int x1ld,
    const float* __restrict__ X2, int x2ld,
    const float* __restrict__ W1, int w1ld,
    const float* __restrict__ W2, int w2ld,
    int k1len, int Ktot, int Jtot,
    float* __restrict__ part)
{
    const int jt = blockIdx.x;
    const int ks = blockIdx.y;
    const int KS = gridDim.y;
    const int kchunk = Ktot / KS;
    const int k0 = ks * kchunk;
    const int t  = threadIdx.x;

    const int c = t & 15;
    const int r = t >> 4;
    const int lane = t & 63;
    const int wj   = t >> 6;
    const int rr   = lane & 15;
    const int kg   = lane >> 4;

    __shared__ __align__(16) ushort Wh[64][72];
    __shared__ __align__(16) ushort Wl[64][72];
    __shared__ __align__(16) ushort Xh[64][72];
    __shared__ __align__(16) ushort Xl[64][72];

    floatx4 acc[4];
#pragma unroll
    for (int bs = 0; bs < 4; ++bs) acc[bs] = (floatx4){0.f, 0.f, 0.f, 0.f};

    for (int kk = k0; kk < k0 + kchunk; kk += 64) {
        const int kg4 = kk + 4 * c;
#pragma unroll
        for (int i = 0; i < 4; ++i) {
            const int row = r + 16 * i;
            const float* xs = (kg4 < k1len) ? (X1 + (size_t)row * x1ld + kg4)
                                            : (X2 + (size_t)row * x2ld + (kg4 - k1len));
            float4 xv = *(const float4*)xs;
            const int j = jt * 64 + row;
            const float* wsrc = (kg4 < k1len) ? (W1 + (size_t)j * w1ld + kg4)
                                              : (W2 + (size_t)j * w2ld + (kg4 - k1len));
            float4 wv = *(const float4*)wsrc;
            stage_split(&Xh[0][0], &Xl[0][0], row, 4 * c, xv);
            stage_split(&Wh[0][0], &Wl[0][0], row, 4 * c, wv);
        }
        __syncthreads();

        const int aoff = (wj * 16 + rr) * 72 + kg * 8;
        short8 ah[2], al[2];
        ah[0] = *(const short8*)((const void*)(&Wh[0][0] + aoff));
        ah[1] = *(const short8*)((const void*)(&Wh[0][0] + aoff + 32));
        al[0] = *(const short8*)((const void*)(&Wl[0][0] + aoff));
        al[1] = *(const short8*)((const void*)(&Wl[0][0] + aoff + 32));

#pragma unroll
        for (int bs = 0; bs < 4; ++bs) {
            const int boff = (bs * 16 + rr) * 72 + kg * 8;
#pragma unroll
            for (int kh = 0; kh < 2; ++kh) {
                short8 bh = *(const short8*)((const void*)(&Xh[0][0] + boff + kh * 32));
                short8 bl = *(const short8*)((const void*)(&Xl[0][0] + boff + kh * 32));
                acc[bs] = MFMA_BF16(ah[kh], bh, acc[bs]);   // hi*hi
                acc[bs] = MFMA_BF16(al[kh], bh, acc[bs]);   // lo*hi
                acc[bs] = MFMA_BF16(ah[kh], bl, acc[bs]);   // hi*lo
            }
        }
        __syncthreads();
    }

    // C/D layout: col = lane&15 (b within subtile), row = (lane>>4)*4 + reg (j within subtile)
    if (STORE_BJ) {
        const int j0 = jt * 64 + wj * 16 + kg * 4;
#pragma unroll
        for (int bs = 0; bs < 4; ++bs) {
            const int b = bs * 16 + rr;
            *(float4*)&part[((size_t)ks * BB + b) * Jtot + j0] =
                (float4){acc[bs][0], acc[bs][1], acc[bs][2], acc[bs][3]};
        }
    } else {
#pragma unroll
        for (int bs = 0; bs < 4; ++bs) {
#pragma unroll
            for (int reg = 0; reg < 4; ++reg) {
                const int j = jt * 64 + wj * 16 + kg * 4 + reg;
                const int b = bs * 16 + rr;
                part[((size_t)ks * Jtot + j) * BB + b] = acc[bs][reg];
            }
        }
    }
}

// LSTM cell from gate partials (layout [ks][j][b]). grid = H/4 = 256 blocks, block = 256.
__global__ __launch_bounds__(256) void lstm_cell(
    const float* __restrict__ part,
    const float* __restrict__ b_ih, const float* __restrict__ b_hh,
    const float* __restrict__ c0, float* __restrict__ yt)
{
    const int t = threadIdx.x;
    const int b = t & 63;
    const int h = blockIdx.x * 4 + (t >> 6);

    float g4[4];
#pragma unroll
    for (int q = 0; q < 4; ++q) {
        const int j = h + q * HH;
        float s = b_ih[j] + b_hh[j];
#pragma unroll
        for (int ks = 0; ks < KS1; ++ks)
            s += part[((size_t)ks * G4H + j) * BB + b];
        g4[q] = s;
    }
    const float ig = sigmoidf_(g4[0]);
    const float fg = sigmoidf_(g4[1]);
    const float gg = tanhf(g4[2]);
    const float og = sigmoidf_(g4[3]);
    const float c  = fg * c0[(size_t)b * HH + h] + ig * gg;
    yt[(size_t)b * HH + h] = og * tanhf(c);
}

// p_t = len * sigmoid( sum_i tanh(t1[b][i]) * v[i] ); window bounds.
// part2 layout [ks][b][i] -> coalesced float4 reads. grid = B, block = 256.
__global__ __launch_bounds__(256) void pos_kernel(
    const float* __restrict__ part2, const float* __restrict__ v,
    const int* __restrict__ elen,
    float* __restrict__ p_out, int* __restrict__ lr_out)
{
    const int b = blockIdx.x;
    const int t = threadIdx.x;

    float4 s = {0.f, 0.f, 0.f, 0.f};
#pragma unroll
    for (int ks = 0; ks < KS2; ++ks) {
        float4 pv = *(const float4*)&part2[((size_t)ks * BB + b) * HH + t * 4];
        s.x += pv.x; s.y += pv.y; s.z += pv.z; s.w += pv.w;
    }
    const float4 vv = *(const float4*)&v[t * 4];
    float acc = tanhf(s.x) * vv.x + tanhf(s.y) * vv.y
              + tanhf(s.z) * vv.z + tanhf(s.w) * vv.w;

    __shared__ float red[256];
    red[t] = acc;
    __syncthreads();
    if (t < 128) red[t] += red[t + 128];
    __syncthreads();
    if (t < 64) {
        float x = red[t] + red[t + 64];
#pragma unroll
        for (int off = 32; off; off >>= 1) x += __shfl_xor(x, off);
        if (t == 0) {
            const float pt  = sigmoidf_(x);
            const float len = (float)elen[b];
            const float p   = len * pt;
            const int   pf  = (int)floorf(p);
            const int   left  = max(0, pf - DD);
            const int   right = min(elen[b], pf + DD);
            p_out[b] = p;
            lr_out[b * 2 + 0] = left;
            lr_out[b * 2 + 1] = right;
        }
    }
}

// Windowed raw scores. grid = (B, 16), block = 256 (4 waves, 2 si each).
// Writes sc[b][0..128) with -1e30 padding beyond window.
__global__ __launch_bounds__(256) void attn_scores(
    const float* __restrict__ encode_h, const float* __restrict__ yt,
    const int* __restrict__ lr, float* __restrict__ sc_out)
{
    const int b = blockIdx.x;
    const int q = blockIdx.y;
    const int t = threadIdx.x;
    const int lane = t & 63;
    const int wv = t >> 6;

    __shared__ float yts[HH];
    *(float4*)&yts[t * 4] = *(const float4*)&yt[(size_t)b * HH + t * 4];
    const int left = lr[b * 2], right = lr[b * 2 + 1];
    const int wsize = right - left;
    __syncthreads();

#pragma unroll
    for (int rr = 0; rr < 2; ++rr) {
        const int si = q * 8 + wv * 2 + rr;
        float s = -1e30f;
        if (si < wsize) {
            const float* eh = encode_h + ((size_t)b * SS + (left + si)) * HH;
            s = 0.0f;
#pragma unroll
            for (int cc = 0; cc < 4; ++cc) {
                const int hb = cc * 256 + lane * 4;
                float4 e = *(const float4*)(eh + hb);
                s += e.x * yts[hb] + e.y * yts[hb + 1] + e.z * yts[hb + 2] + e.w * yts[hb + 3];
            }
#pragma unroll
            for (int off = 32; off; off >>= 1) s += __shfl_xor(s, off);
        }
        if (lane == 0) sc_out[b * 2 * DD + si] = s;
    }
}

// Fused softmax+gauss+ct: grid = (B, 8), block = 512 = 4 si-quarters x 128 h.
__global__ __launch_bounds__(512) void attn_ct(
    const float* __restrict__ encode_h, const float* __restrict__ sc,
    const float* __restrict__ p_buf, const int* __restrict__ lr,
    float* __restrict__ ct)
{
    const int b = blockIdx.x;
    const int t = threadIdx.x;
    const int lane = t & 63;
    const int hh = t & 127;          // h within 128-chunk
    const int q  = t >> 7;           // si-quarter 0..3
    const int h = blockIdx.y * 128 + hh;

    __shared__ float scs[2 * DD];
    __shared__ float ats[2 * DD];
    __shared__ float red[4][128];

    const int left = lr[b * 2];
    if (t < 2 * DD) scs[t] = sc[b * 2 * DD + t];
    __syncthreads();

    float m = fmaxf(scs[lane], scs[lane + 64]);
#pragma unroll
    for (int off = 32; off; off >>= 1) m = fmaxf(m, __shfl_xor(m, off));
    float ssum = expf(scs[lane] - m) + expf(scs[lane + 64] - m);
#pragma unroll
    for (int off = 32; off; off >>= 1) ssum += __shfl_xor(ssum, off);
    const float inv = 1.0f / ssum;

    if (t < 2 * DD) {
        const float dj = (float)(left + t) - p_buf[b];
        ats[t] = expf(scs[t] - m) * inv * expf(-(dj * dj) * (1.0f / 2048.0f));
    }
    __syncthreads();

    const float* ehb = encode_h + ((size_t)b * SS + left + q * 32) * HH + h;
    const float* atp = &ats[q * 32];
    float a0 = 0, a1 = 0, a2 = 0, a3 = 0, a4 = 0, a5 = 0, a6 = 0, a7 = 0;
#pragma unroll
    for (int si = 0; si < 32; si += 8) {
        a0 = fmaf(atp[si + 0], ehb[(size_t)(si + 0) * HH], a0);
        a1 = fmaf(atp[si + 1], ehb[(size_t)(si + 1) * HH], a1);
        a2 = fmaf(atp[si + 2], ehb[(size_t)(si + 2) * HH], a2);
        a3 = fmaf(atp[si + 3], ehb[(size_t)(si + 3) * HH], a3);
        a4 = fmaf(atp[si + 4], ehb[(size_t)(si + 4) * HH], a4);
        a5 = fmaf(atp[si + 5], ehb[(size_t)(si + 5) * HH], a5);
        a6 = fmaf(atp[si + 6], ehb[(size_t)(si + 6) * HH], a6);
        a7 = fmaf(atp[si + 7], ehb[(size_t)(si + 7) * HH], a7);
    }
    const float a = ((a0 + a1) + (a2 + a3)) + ((a4 + a5) + (a6 + a7));

    if (q != 0) red[q][hh] = a;
    __syncthreads();
    if (q == 0)
        ct[(size_t)b * HH + h] = (a + red[1][hh]) + (red[2][hh] + red[3][hh]);
}

// out[b][j] = sum_ks part3[ks][j][b].  grid = H/4 = 256, block = 256 (coalesced reads).
__global__ __launch_bounds__(256) void reduce_out(
    const float* __restrict__ part3, float* __restrict__ out)
{
    const int t = threadIdx.x;
    const int b = t & 63;
    const int j = blockIdx.x * 4 + (t >> 6);
    float s = 0.0f;
#pragma unroll
    for (int ks = 0; ks < KS2; ++ks)
        s += part3[((size_t)ks * HH + j) * BB + b];
    out[(size_t)b * HH + j] = s;
}

extern "C" void kernel_launch(void* const* d_in, const int* in_sizes, int n_in,
                              void* d_out, int out_size, void* d_ws, size_t ws_size,
                              hipStream_t stream)
{
    const float* encode_h = (const float*)d_in[0];
    const float* x_t      = (const float*)d_in[1];
    const float* h0       = (const float*)d_in[2];
    const float* c0       = (const float*)d_in[3];
    const float* W_ih     = (const float*)d_in[4];
    const float* W_hh     = (const float*)d_in[5];
    const float* b_ih     = (const float*)d_in[6];
    const float* b_hh     = (const float*)d_in[7];
    const float* W_ht2tan = (const float*)d_in[8];
    const float* W_tan2pt = (const float*)d_in[9];
    const float* W_ct2ht  = (const float*)d_in[10];
    const int*   elen     = (const int*)d_in[11];
    float* out = (float*)d_out;

    float* ws = (float*)d_ws;
    float* gates_part = ws;                                   // KS1*4096*64 = 4M floats
    float* yt    = gates_part + (size_t)KS1 * G4H * BB;       // 65536
    float* part2 = yt + (size_t)BB * HH;                      // KS2*1024*64 = 1M
    float* pbuf  = part2 + (size_t)KS2 * HH * BB;             // 64
    int*   lrbuf = (int*)(pbuf + BB);                         // 128 ints
    float* scbuf = pbuf + BB + 2 * BB;                        // 64*128
    float* ctbuf = scbuf + (size_t)BB * 2 * DD;               // 65536
    float* part3 = ctbuf + (size_t)BB * HH;                   // KS2*1024*64 = 1M

    // K1: gates partial GEMM (K = 2048 | 1024 concat), grid (64,16) = 1024 blocks (4/CU)
    dim3 g1(G4H / 64, KS1);
    gemm_mfma<false><<<g1, 256, 0, stream>>>(x_t, EE + HH, h0, HH,
                                             W_ih, EE + HH, W_hh, HH,
                                             2048, 3072, G4H, gates_part);
    // K2: LSTM cell -> yt
    lstm_cell<<<HH / 4, 256, 0, stream>>>(gates_part, b_ih, b_hh, c0, yt);

    // K3a: t1 = yt @ W_ht2tan^T (partials, [ks][b][j] layout), grid (16,16) = 256 blocks
    dim3 g3(HH / 64, KS2);
    gemm_mfma<true><<<g3, 256, 0, stream>>>(yt, HH, yt, HH,
                                            W_ht2tan, HH, W_ht2tan, HH,
                                            HH, HH, HH, part2);
    // K3b: p, window bounds (coalesced float4 reads of part2)
    pos_kernel<<<BB, 256, 0, stream>>>(part2, W_tan2pt, elen, pbuf, lrbuf);

    // K4a: windowed raw scores, grid (64,16) = 1024 blocks (2 si per wave)
    dim3 g4a(BB, 16);
    attn_scores<<<g4a, 256, 0, stream>>>(encode_h, yt, lrbuf, scbuf);
    // K4b: softmax + gauss + ct, grid (64,8) = 512 blocks, block 512
    dim3 g4b(BB, 8);
    attn_ct<<<g4b, 512, 0, stream>>>(encode_h, scbuf, pbuf, lrbuf, ctbuf);

    // K5: ht partials = ct @ W_ct2ht^T, grid (16,16), [ks][j][b] layout
    gemm_mfma<false><<<g3, 256, 0, stream>>>(ctbuf, HH, ctbuf, HH,
                                             W_ct2ht, HH, W_ct2ht, HH,
                                             HH, HH, HH, part3);
    // K6: reduce -> out
    reduce_out<<<HH / 4, 256, 0, stream>>>(part3, out);
}